// Round 1
// baseline (17003.612 us; speedup 1.0000x reference)
//
#include <hip/hip_runtime.h>
#include <hip/hip_bf16.h>
#include <math.h>

#define GF_RELU 1
#define GF_RES  2

// ---------------------------------------------------------------------------
// fp32 tiled GEMM: C[M,N] = A[M,K] @ W[N,K]^T + bias[N] (+R) (relu)
// 128x128 tile, BK=8, 256 threads, 8x8 accumulators per thread.
// ---------------------------------------------------------------------------
__global__ __launch_bounds__(256)
void gemm_f32(const float* __restrict__ A, const float* __restrict__ W,
              const float* __restrict__ bias, const float* __restrict__ R,
              float* __restrict__ C, int M, int N, int K, int flags)
{
    __shared__ float As[8][128];
    __shared__ float Ws[8][128];
    const int tid = threadIdx.x;
    const int m0 = blockIdx.y * 128, n0 = blockIdx.x * 128;
    const int lr = tid >> 1;           // 0..127 row within tile
    const int lk = (tid & 1) * 4;      // 0 or 4
    const int tx = tid & 15, ty = tid >> 4;

    float acc[8][8];
#pragma unroll
    for (int i = 0; i < 8; ++i)
#pragma unroll
        for (int j = 0; j < 8; ++j) acc[i][j] = 0.f;

    for (int k0 = 0; k0 < K; k0 += 8) {
        float4 av = make_float4(0.f, 0.f, 0.f, 0.f);
        float4 wv = make_float4(0.f, 0.f, 0.f, 0.f);
        const int gm = m0 + lr, gn = n0 + lr, kk = k0 + lk;
        if (gm < M) {
            if (kk + 3 < K) {
                av = *(const float4*)(A + (size_t)gm * K + kk);
            } else {
                const float* p = A + (size_t)gm * K;
                float t[4] = {0.f, 0.f, 0.f, 0.f};
                for (int j = 0; j < 4; ++j) if (kk + j < K) t[j] = p[kk + j];
                av = make_float4(t[0], t[1], t[2], t[3]);
            }
        }
        if (gn < N) {
            if (kk + 3 < K) {
                wv = *(const float4*)(W + (size_t)gn * K + kk);
            } else {
                const float* p = W + (size_t)gn * K;
                float t[4] = {0.f, 0.f, 0.f, 0.f};
                for (int j = 0; j < 4; ++j) if (kk + j < K) t[j] = p[kk + j];
                wv = make_float4(t[0], t[1], t[2], t[3]);
            }
        }
        __syncthreads();   // protect previous iteration's compute
        As[lk + 0][lr] = av.x; As[lk + 1][lr] = av.y;
        As[lk + 2][lr] = av.z; As[lk + 3][lr] = av.w;
        Ws[lk + 0][lr] = wv.x; Ws[lk + 1][lr] = wv.y;
        Ws[lk + 2][lr] = wv.z; Ws[lk + 3][lr] = wv.w;
        __syncthreads();
#pragma unroll
        for (int k2 = 0; k2 < 8; ++k2) {
            float a[8], w[8];
            *(float4*)(a)     = *(const float4*)&As[k2][ty * 4];
            *(float4*)(a + 4) = *(const float4*)&As[k2][ty * 4 + 64];
            *(float4*)(w)     = *(const float4*)&Ws[k2][tx * 4];
            *(float4*)(w + 4) = *(const float4*)&Ws[k2][tx * 4 + 64];
#pragma unroll
            for (int i = 0; i < 8; ++i)
#pragma unroll
                for (int j = 0; j < 8; ++j) acc[i][j] += a[i] * w[j];
        }
    }

    // epilogue
#pragma unroll
    for (int ih = 0; ih < 2; ++ih) {
#pragma unroll
        for (int i = 0; i < 4; ++i) {
            const int gm = m0 + ih * 64 + ty * 4 + i;
            if (gm >= M) continue;
            const int ai = ih * 4 + i;
#pragma unroll
            for (int jh = 0; jh < 2; ++jh) {
                const int gn0 = n0 + jh * 64 + tx * 4;
                if (gn0 >= N) continue;
                float vv[4];
#pragma unroll
                for (int j = 0; j < 4; ++j) vv[j] = acc[ai][jh * 4 + j];
                if (gn0 + 3 < N) {
                    if (bias) {
                        vv[0] += bias[gn0];     vv[1] += bias[gn0 + 1];
                        vv[2] += bias[gn0 + 2]; vv[3] += bias[gn0 + 3];
                    }
                    if (flags & GF_RES) {
                        const float4 rv = *(const float4*)(R + (size_t)gm * N + gn0);
                        vv[0] += rv.x; vv[1] += rv.y; vv[2] += rv.z; vv[3] += rv.w;
                    }
                    if (flags & GF_RELU)
                        for (int j = 0; j < 4; ++j) vv[j] = fmaxf(vv[j], 0.f);
                    *(float4*)(C + (size_t)gm * N + gn0) =
                        make_float4(vv[0], vv[1], vv[2], vv[3]);
                } else {
                    for (int j = 0; j < 4; ++j) {
                        const int gn = gn0 + j;
                        if (gn >= N) break;
                        float v = vv[j] + (bias ? bias[gn] : 0.f);
                        if (flags & GF_RES) v += R[(size_t)gm * N + gn];
                        if (flags & GF_RELU) v = fmaxf(v, 0.f);
                        C[(size_t)gm * N + gn] = v;
                    }
                }
            }
        }
    }
}

// ---------------------------------------------------------------------------
// FSMN sliding-window mean: means[b,i,d] = mean(H[b, max(0,i-stride)..i, d])
// One thread per (b, d, chunk); O(1) sliding-window update per row.
// grid (D/256, L/CH, B), block 256.
// ---------------------------------------------------------------------------
__global__ __launch_bounds__(256)
void fsmn_means(const float* __restrict__ H, float* __restrict__ Mn, int stride)
{
    const int L = 2048, D = 512, CH = 256;
    const int d = blockIdx.x * 256 + threadIdx.x;
    const int b = blockIdx.z;
    const int c0 = blockIdx.y * CH;
    const float* Hb = H + (size_t)b * L * D + d;
    float* Mb = Mn + (size_t)b * L * D + d;
    float sum = 0.f;
    int s0 = c0 - stride; if (s0 < 0) s0 = 0;
    for (int j = s0; j < c0; ++j) sum += Hb[(size_t)j * D];
    for (int i = c0; i < c0 + CH; ++i) {
        sum += Hb[(size_t)i * D];
        const int st = i - stride;
        const float cnt = (float)(i + 1 - (st > 0 ? st : 0));
        Mb[(size_t)i * D] = sum / cnt;
        if (st >= 0) sum -= Hb[(size_t)st * D];
    }
}

// ---------------------------------------------------------------------------
// ci[b,l,s] = dot(H[b,l,:], SF[b,s,:])   (D=512, S=4)
// ---------------------------------------------------------------------------
__global__ __launch_bounds__(256)
void ci_kernel(const float* __restrict__ H, const float* __restrict__ SF,
               float* __restrict__ CI)
{
    const int idx = blockIdx.x * 256 + threadIdx.x;   // B*L*S = 65536
    const int s = idx & 3;
    const int bl = idx >> 2;
    const int b = bl >> 11;
    const float4* h = (const float4*)(H + (size_t)bl * 512);
    const float4* f = (const float4*)(SF + ((size_t)b * 4 + s) * 512);
    float acc = 0.f;
    for (int k = 0; k < 128; ++k) {
        const float4 a = h[k], w = f[k];
        acc += a.x * w.x + a.y * w.y + a.z * w.z + a.w * w.w;
    }
    CI[idx] = acc;
}

// ---------------------------------------------------------------------------
// Fused residual-add + LayerNorm over D=512. One wave per row, 4 rows/block.
// Y = LN(X + R) * w + b
// ---------------------------------------------------------------------------
__global__ __launch_bounds__(256)
void ln_add_f32(const float* __restrict__ X, const float* __restrict__ R,
                const float* __restrict__ w, const float* __restrict__ b,
                float* __restrict__ Y)
{
    const int lane = threadIdx.x & 63, wid = threadIdx.x >> 6;
    const size_t row = (size_t)blockIdx.x * 4 + wid;
    const float* x = X + row * 512;
    const float* r = R + row * 512;
    const int c0 = lane * 8;
    float v[8];
    {
        const float4 a0 = *(const float4*)(x + c0);
        const float4 a1 = *(const float4*)(x + c0 + 4);
        const float4 r0 = *(const float4*)(r + c0);
        const float4 r1 = *(const float4*)(r + c0 + 4);
        v[0] = a0.x + r0.x; v[1] = a0.y + r0.y; v[2] = a0.z + r0.z; v[3] = a0.w + r0.w;
        v[4] = a1.x + r1.x; v[5] = a1.y + r1.y; v[6] = a1.z + r1.z; v[7] = a1.w + r1.w;
    }
    float s = 0.f;
#pragma unroll
    for (int j = 0; j < 8; ++j) s += v[j];
#pragma unroll
    for (int off = 1; off < 64; off <<= 1) s += __shfl_xor(s, off);
    const float mean = s * (1.f / 512.f);
    float q = 0.f;
#pragma unroll
    for (int j = 0; j < 8; ++j) { const float dd = v[j] - mean; q += dd * dd; }
#pragma unroll
    for (int off = 1; off < 64; off <<= 1) q += __shfl_xor(q, off);
    const float rstd = rsqrtf(q * (1.f / 512.f) + 1e-5f);
    float* y = Y + row * 512;
#pragma unroll
    for (int j = 0; j < 8; ++j)
        y[c0 + j] = (v[j] - mean) * rstd * w[c0 + j] + b[c0 + j];
}

// ---------------------------------------------------------------------------
// Flash attention fp32. NHEAD=4, hd=128, L=2048. One block = (b,h,16 q-rows).
// K/V staged in LDS in 64-key tiles; online softmax.
// ---------------------------------------------------------------------------
__global__ __launch_bounds__(256)
void attn_f32(const float* __restrict__ QKV, float* __restrict__ O)
{
    const int L = 2048, DM = 1536, HD = 128;
    __shared__ float Ks[64][132];
    __shared__ float Vs[64][132];
    __shared__ float Qs[16][132];
    __shared__ float Sc[16][68];
    __shared__ float mrow[16], lrow[16], crow[16];

    const int tid = threadIdx.x;
    const int q0 = blockIdx.x * 16;
    const int b = blockIdx.y >> 2, h = blockIdx.y & 3;
    const size_t base = (size_t)b * L * DM + (size_t)h * HD;

    // load Q tile (16x128)
#pragma unroll
    for (int i = 0; i < 2; ++i) {
        const int e = tid + i * 256;       // float4 index 0..511
        const int row = e >> 5, c4 = e & 31;
        const float4 v = *(const float4*)(QKV + base + (size_t)(q0 + row) * DM + c4 * 4);
        *(float4*)&Qs[row][c4 * 4] = v;
    }
    if (tid < 16) { mrow[tid] = -1e30f; lrow[tid] = 0.f; }

    float o[8] = {0.f, 0.f, 0.f, 0.f, 0.f, 0.f, 0.f, 0.f};
    const int c = tid & 63, rg = (tid >> 6) * 4;     // scores mapping
    const int r = tid >> 4, cg = tid & 15;           // softmax mapping
    const int r2 = tid & 15, db = (tid >> 4) * 8;    // PV mapping
    const float SCALE = 0.08838834764831845f;        // 1/sqrt(128)

    for (int kt = 0; kt < 32; ++kt) {
        const int k0 = kt * 64;
        __syncthreads();
        // stage K,V tile (64x128 each)
#pragma unroll
        for (int i = 0; i < 8; ++i) {
            const int e = tid + i * 256;    // float4 index 0..2047
            const int row = e >> 5, c4 = e & 31;
            const size_t g = base + (size_t)(k0 + row) * DM + c4 * 4;
            *(float4*)&Ks[row][c4 * 4] = *(const float4*)(QKV + g + 512);
            *(float4*)&Vs[row][c4 * 4] = *(const float4*)(QKV + g + 1024);
        }
        __syncthreads();
        // scores: thread computes 4 (row, key=c) dots of length 128
        {
            float sc[4] = {0.f, 0.f, 0.f, 0.f};
            for (int k4 = 0; k4 < 32; ++k4) {
                const float4 kv = *(const float4*)&Ks[c][k4 * 4];
#pragma unroll
                for (int rr = 0; rr < 4; ++rr) {
                    const float4 qv = *(const float4*)&Qs[rg + rr][k4 * 4];
                    sc[rr] += qv.x * kv.x + qv.y * kv.y + qv.z * kv.z + qv.w * kv.w;
                }
            }
#pragma unroll
            for (int rr = 0; rr < 4; ++rr) Sc[rg + rr][c] = sc[rr] * SCALE;
        }
        __syncthreads();
        // online softmax partial (16 lanes per row)
        {
            float4 pv = *(const float4*)&Sc[r][cg * 4];
            float mx = fmaxf(fmaxf(pv.x, pv.y), fmaxf(pv.z, pv.w));
#pragma unroll
            for (int off = 1; off < 16; off <<= 1) mx = fmaxf(mx, __shfl_xor(mx, off));
            const float nm = fmaxf(mrow[r], mx);
            float4 e4;
            e4.x = __expf(pv.x - nm); e4.y = __expf(pv.y - nm);
            e4.z = __expf(pv.z - nm); e4.w = __expf(pv.w - nm);
            *(float4*)&Sc[r][cg * 4] = e4;
            float sm = e4.x + e4.y + e4.z + e4.w;
#pragma unroll
            for (int off = 1; off < 16; off <<= 1) sm += __shfl_xor(sm, off);
            if (cg == 0) {
                const float corr = __expf(mrow[r] - nm);
                crow[r] = corr;
                lrow[r] = lrow[r] * corr + sm;
                mrow[r] = nm;
            }
        }
        __syncthreads();
        // PV: o[r2, db..db+7] accumulate
        {
            const float cr = crow[r2];
#pragma unroll
            for (int j = 0; j < 8; ++j) o[j] *= cr;
            for (int cc = 0; cc < 64; ++cc) {
                const float p = Sc[r2][cc];
                const float4 va = *(const float4*)&Vs[cc][db];
                const float4 vb = *(const float4*)&Vs[cc][db + 4];
                o[0] += p * va.x; o[1] += p * va.y; o[2] += p * va.z; o[3] += p * va.w;
                o[4] += p * vb.x; o[5] += p * vb.y; o[6] += p * vb.z; o[7] += p * vb.w;
            }
        }
    }
    const float inv = 1.0f / lrow[r2];
    float* dst = O + ((size_t)(b * L + q0 + r2) * 512) + h * HD + db;
    float4 w0, w1;
    w0.x = o[0] * inv; w0.y = o[1] * inv; w0.z = o[2] * inv; w0.w = o[3] * inv;
    w1.x = o[4] * inv; w1.y = o[5] * inv; w1.z = o[6] * inv; w1.w = o[7] * inv;
    *(float4*)dst = w0;
    *(float4*)(dst + 4) = w1;
}

// ---------------------------------------------------------------------------
// concat([ci (B,L,4), cd (B,L,512)], axis=2) -> [B,L,516]
// ---------------------------------------------------------------------------
__global__ __launch_bounds__(256)
void concat_kernel(const float* __restrict__ CI, const float* __restrict__ CD,
                   float* __restrict__ OUTC)
{
    const size_t total = (size_t)16384 * 516;
    size_t i = (size_t)blockIdx.x * 256 + threadIdx.x;
    if (i >= total) return;
    const int col = (int)(i % 516);
    const size_t rowi = i / 516;
    OUTC[i] = (col < 4) ? CI[rowi * 4 + col] : CD[rowi * 512 + (col - 4)];
}

// ---------------------------------------------------------------------------
extern "C" void kernel_launch(void* const* d_in, const int* in_sizes, int n_in,
                              void* d_out, int out_size, void* d_ws, size_t ws_size,
                              hipStream_t stream)
{
    (void)in_sizes; (void)n_in; (void)out_size; (void)ws_size;
    const int B = 8, L = 2048, D = 512;
    const int M = B * L;                 // 16384

    const float* x        = (const float*)d_in[0];
    const float* spk_emb  = (const float*)d_in[1];
    const float* enc0_w   = (const float*)d_in[2];
    const float* enc0_b   = (const float*)d_in[3];
    const float* enc_lw   = (const float*)d_in[4];
    const float* enc_lb   = (const float*)d_in[5];
    const float* enc_mw   = (const float*)d_in[6];
    const float* enc_mb   = (const float*)d_in[7];
    const float* spk_w1   = (const float*)d_in[8];
    const float* spk_b1   = (const float*)d_in[9];
    const float* spk_w2   = (const float*)d_in[10];
    const float* spk_b2   = (const float*)d_in[11];
    const float* spk_w3   = (const float*)d_in[12];
    const float* spk_b3   = (const float*)d_in[13];
    const float* tr_in_w  = (const float*)d_in[14];
    const float* tr_in_b  = (const float*)d_in[15];
    const float* tr_out_w = (const float*)d_in[16];
    const float* tr_out_b = (const float*)d_in[17];
    const float* tr_ln1_w = (const float*)d_in[18];
    const float* tr_ln1_b = (const float*)d_in[19];
    const float* tr_ff1_w = (const float*)d_in[20];
    const float* tr_ff1_b = (const float*)d_in[21];
    const float* tr_ff2_w = (const float*)d_in[22];
    const float* tr_ff2_b = (const float*)d_in[23];
    const float* tr_ln2_w = (const float*)d_in[24];
    const float* tr_ln2_b = (const float*)d_in[25];
    const float* adpt_w   = (const float*)d_in[26];
    const float* adpt_b   = (const float*)d_in[27];
    const float* post_lw  = (const float*)d_in[28];
    const float* post_lb  = (const float*)d_in[29];
    const float* post_mw  = (const float*)d_in[30];
    const float* post_mb  = (const float*)d_in[31];
    const float* cls_w1   = (const float*)d_in[32];
    const float* cls_b1   = (const float*)d_in[33];
    const float* cls_w2   = (const float*)d_in[34];
    const float* cls_b2   = (const float*)d_in[35];

    // ---- workspace layout (floats) ----
    float* ws = (float*)d_ws;
    size_t off = 0;
    float* H  = ws + off; off += (size_t)M * 512;   // 8,388,608
    float* T1 = ws + off; off += (size_t)M * 516;   // [M,516] capacity
    float* T2 = ws + off; off += (size_t)M * 516;
    float* F  = ws + off; off += (size_t)M * 2048;  // FFN hidden / QKV+O
    float* S1 = ws + off; off += 32 * 512;
    float* S2 = ws + off; off += 32 * 512;
    float* S3 = ws + off; off += 32 * 512;
    float* CI = ws + off; off += (size_t)M * 4;
    float* QKV = F;
    float* AO  = F + (size_t)M * 1536;              // attn output packs after QKV

    auto gemm = [&](const float* A, const float* W, const float* bias,
                    const float* R, float* C, int m, int n, int k, int flags) {
        dim3 g((n + 127) / 128, (m + 127) / 128);
        hipLaunchKernelGGL(gemm_f32, g, dim3(256), 0, stream,
                           A, W, bias, R, C, m, n, k, flags);
    };

    // 1. encoder input projection: [M,80] -> [M,512]
    gemm(x, enc0_w, enc0_b, nullptr, H, M, 512, 80, 0);

    // 2. 8 encoder FSMN layers, strides 1,2,...,128
    for (int i = 0; i < 8; ++i) {
        const int stride = 1 << i;
        gemm(H, enc_lw + (size_t)i * 512 * 512, enc_lb + (size_t)i * 512,
             nullptr, T1, M, 512, 512, 0);
        hipLaunchKernelGGL(fsmn_means, dim3(2, 8, 8), dim3(256), 0, stream,
                           H, T2, stride);
        gemm(T2, enc_mw + (size_t)i * 512 * 512, enc_mb + (size_t)i * 512,
             T1, H, M, 512, 512, GF_RES);
    }

    // 3. speaker MLP: [32,192] -> 512 -> 512 -> 512
    gemm(spk_emb, spk_w1, spk_b1, nullptr, S1, 32, 512, 192, GF_RELU);
    gemm(S1, spk_w2, spk_b2, nullptr, S2, 32, 512, 512, GF_RELU);
    gemm(S2, spk_w3, spk_b3, nullptr, S3, 32, 512, 512, 0);

    // 4. context-independent scores ci[b,l,s]
    hipLaunchKernelGGL(ci_kernel, dim3(65536 / 256), dim3(256), 0, stream,
                       H, S3, CI);

    // 5. 4 transformer layers (in-place on H)
    for (int i = 0; i < 4; ++i) {
        gemm(H, tr_in_w + (size_t)i * 1536 * 512, tr_in_b + (size_t)i * 1536,
             nullptr, QKV, M, 1536, 512, 0);
        hipLaunchKernelGGL(attn_f32, dim3(L / 16, B * 4), dim3(256), 0, stream,
                           QKV, AO);
        gemm(AO, tr_out_w + (size_t)i * 512 * 512, tr_out_b + (size_t)i * 512,
             nullptr, T1, M, 512, 512, 0);
        hipLaunchKernelGGL(ln_add_f32, dim3(M / 4), dim3(256), 0, stream,
                           H, T1, tr_ln1_w + (size_t)i * 512, tr_ln1_b + (size_t)i * 512, H);
        gemm(H, tr_ff1_w + (size_t)i * 2048 * 512, tr_ff1_b + (size_t)i * 2048,
             nullptr, F, M, 2048, 512, GF_RELU);
        gemm(F, tr_ff2_w + (size_t)i * 512 * 2048, tr_ff2_b + (size_t)i * 512,
             nullptr, T1, M, 512, 2048, 0);
        hipLaunchKernelGGL(ln_add_f32, dim3(M / 4), dim3(256), 0, stream,
                           H, T1, tr_ln2_w + (size_t)i * 512, tr_ln2_b + (size_t)i * 512, H);
    }

    // 6. concat + adapter: [M,516] -> [M,512]
    {
        const size_t total = (size_t)M * 516;
        hipLaunchKernelGGL(concat_kernel, dim3((unsigned)((total + 255) / 256)),
                           dim3(256), 0, stream, CI, H, T2);
        gemm(T2, adpt_w, adpt_b, nullptr, H, M, 512, 516, 0);
    }

    // 7. 6 post FSMN layers, strides 1,2,4,8,16,32
    for (int i = 0; i < 6; ++i) {
        const int stride = 1 << i;
        gemm(H, post_lw + (size_t)i * 512 * 512, post_lb + (size_t)i * 512,
             nullptr, T1, M, 512, 512, 0);
        hipLaunchKernelGGL(fsmn_means, dim3(2, 8, 8), dim3(256), 0, stream,
                           H, T2, stride);
        gemm(T2, post_mw + (size_t)i * 512 * 512, post_mb + (size_t)i * 512,
             T1, H, M, 512, 512, GF_RES);
    }

    // 8. classifier: relu(H @ cls_w1 + b1) @ cls_w2 + b2 -> d_out [M,16]
    gemm(H, cls_w1, cls_b1, nullptr, T1, M, 512, 512, GF_RELU);
    gemm(T1, cls_w2, cls_b2, nullptr, (float*)d_out, M, 16, 512, 0);
}

// Round 3
// 5968.916 us; speedup vs baseline: 2.8487x; 2.8487x over previous
//
#include <hip/hip_runtime.h>
#include <hip/hip_bf16.h>
#include <math.h>

typedef unsigned short u16t;
using f32x4 = __attribute__((ext_vector_type(4))) float;
using s16x8 = __attribute__((ext_vector_type(8))) short;
using us8   = __attribute__((ext_vector_type(8))) unsigned short;

#define GB_RELU 1
#define GB_RES  2
#define GB_WF32 4
#define GB_WB16 8

__device__ __forceinline__ u16t f2b(float f) {
    unsigned u = __float_as_uint(f);
    unsigned r = (u + 0x7FFFu + ((u >> 16) & 1u)) >> 16;
    return (u16t)r;
}
__device__ __forceinline__ float b2f(u16t s) {
    return __uint_as_float(((unsigned)s) << 16);
}
__device__ __forceinline__ void gload16(const void* gsrc, void* ldst) {
    __builtin_amdgcn_global_load_lds(
        (const __attribute__((address_space(1))) void*)gsrc,
        (__attribute__((address_space(3))) void*)ldst, 16, 0, 0);
}

// ---------------------------------------------------------------------------
// bf16 MFMA GEMM: C[M,N] = A[M,K](bf16) @ W[N,K]^T(bf16) + bias + R, relu opt.
// 128x128 tile, BK=64, 256 thr (4 waves, 2x2), LDS layout [kblk][row][8].
// Requires K%64==0, N%128==0. M arbitrary (row-clamped loads, masked stores).
// ---------------------------------------------------------------------------
__global__ __launch_bounds__(256)
void gemm_bf16(const u16t* __restrict__ A, int lda,
               const u16t* __restrict__ W, int ldw,
               const float* __restrict__ bias, const float* __restrict__ R,
               float* __restrict__ C, u16t* __restrict__ Cb,
               int M, int N, int K, int flags)
{
    __shared__ u16t As[8192];
    __shared__ u16t Ws[8192];
    const int tid = threadIdx.x;
    const int lane = tid & 63, w = tid >> 6;
    const int wr = w >> 1, wc = w & 1;
    const int l15 = lane & 15, l4 = lane >> 4;
    const int m0 = blockIdx.y * 128, n0 = blockIdx.x * 128;

    f32x4 acc[4][4];
#pragma unroll
    for (int i = 0; i < 4; ++i)
#pragma unroll
        for (int j = 0; j < 4; ++j) acc[i][j] = (f32x4){0.f, 0.f, 0.f, 0.f};

    for (int k0 = 0; k0 < K; k0 += 64) {
#pragma unroll
        for (int it = 0; it < 4; ++it) {
            const int e = it * 256 + tid;
            const int e0 = it * 256 + (tid & 192);
            const int kb = e >> 7, r = e & 127;
            int gm = m0 + r; if (gm > M - 1) gm = M - 1;
            gload16(A + (size_t)gm * lda + k0 + kb * 8, &As[(size_t)e0 * 8]);
        }
#pragma unroll
        for (int it = 0; it < 4; ++it) {
            const int e = it * 256 + tid;
            const int e0 = it * 256 + (tid & 192);
            const int kb = e >> 7, r = e & 127;
            gload16(W + (size_t)(n0 + r) * ldw + k0 + kb * 8, &Ws[(size_t)e0 * 8]);
        }
        __syncthreads();
#pragma unroll
        for (int kk = 0; kk < 2; ++kk) {
            const int kb = kk * 4 + l4;
            s16x8 a[4], b[4];
#pragma unroll
            for (int mi = 0; mi < 4; ++mi)
                a[mi] = *(const s16x8*)&As[(size_t)(kb * 128 + wr * 64 + mi * 16 + l15) * 8];
#pragma unroll
            for (int ni = 0; ni < 4; ++ni)
                b[ni] = *(const s16x8*)&Ws[(size_t)(kb * 128 + wc * 64 + ni * 16 + l15) * 8];
#pragma unroll
            for (int mi = 0; mi < 4; ++mi)
#pragma unroll
                for (int ni = 0; ni < 4; ++ni)
                    acc[mi][ni] = __builtin_amdgcn_mfma_f32_16x16x32_bf16(
                        a[mi], b[ni], acc[mi][ni], 0, 0, 0);
        }
        __syncthreads();
    }

#pragma unroll
    for (int mi = 0; mi < 4; ++mi) {
#pragma unroll
        for (int r = 0; r < 4; ++r) {
            const int row = m0 + wr * 64 + mi * 16 + l4 * 4 + r;
            if (row >= M) continue;
#pragma unroll
            for (int ni = 0; ni < 4; ++ni) {
                const int col = n0 + wc * 64 + ni * 16 + l15;
                float v = acc[mi][ni][r];
                if (bias) v += bias[col];
                if (flags & GB_RES) v += R[(size_t)row * N + col];
                if (flags & GB_RELU) v = fmaxf(v, 0.f);
                if (flags & GB_WF32) C[(size_t)row * N + col] = v;
                if (flags & GB_WB16) Cb[(size_t)row * N + col] = f2b(v);
            }
        }
    }
}

// ---------------------------------------------------------------------------
// FSMN sliding-window mean on bf16 activations (fp32 running sum).
// grid (2, 8, 8) = (D/256, L/256, B), block 256.
// ---------------------------------------------------------------------------
__global__ __launch_bounds__(256)
void fsmn_means_b(const u16t* __restrict__ Hb, u16t* __restrict__ Mb, int stride)
{
    const int d = blockIdx.x * 256 + threadIdx.x;
    const int b = blockIdx.z;
    const int c0 = blockIdx.y * 256;
    const u16t* Hp = Hb + (size_t)b * 2048 * 512 + d;
    u16t* Mp = Mb + (size_t)b * 2048 * 512 + d;
    float sum = 0.f;
    int s0 = c0 - stride; if (s0 < 0) s0 = 0;
    for (int j = s0; j < c0; ++j) sum += b2f(Hp[(size_t)j * 512]);
    for (int i = c0; i < c0 + 256; ++i) {
        sum += b2f(Hp[(size_t)i * 512]);
        const int st = i - stride;
        const float cnt = (float)(i + 1 - (st > 0 ? st : 0));
        Mp[(size_t)i * 512] = f2b(sum / cnt);
        if (st >= 0) sum -= b2f(Hp[(size_t)st * 512]);
    }
}

// ---------------------------------------------------------------------------
// ci[b,l,s] = dot(Hb[b,l,:], SF[b,s,:])
// ---------------------------------------------------------------------------
__global__ __launch_bounds__(256)
void ci_kernel(const u16t* __restrict__ Hb, const float* __restrict__ SF,
               float* __restrict__ CI)
{
    const int idx = blockIdx.x * 256 + threadIdx.x;   // 65536
    const int s = idx & 3;
    const int bl = idx >> 2;
    const int b = bl >> 11;
    const us8* h8 = (const us8*)(Hb + (size_t)bl * 512);
    const float4* f4 = (const float4*)(SF + ((size_t)(b * 4 + s)) * 512);
    float acc = 0.f;
    for (int k = 0; k < 64; ++k) {
        const us8 hv = h8[k];
        const float4 f0 = f4[k * 2], f1 = f4[k * 2 + 1];
        acc += b2f(hv[0]) * f0.x + b2f(hv[1]) * f0.y + b2f(hv[2]) * f0.z + b2f(hv[3]) * f0.w
             + b2f(hv[4]) * f1.x + b2f(hv[5]) * f1.y + b2f(hv[6]) * f1.z + b2f(hv[7]) * f1.w;
    }
    CI[idx] = acc;
}

// ---------------------------------------------------------------------------
// Y = LN(X + R) * w + b ; writes fp32 Y and bf16 Yb. One wave per row.
// ---------------------------------------------------------------------------
__global__ __launch_bounds__(256)
void ln_add_f32(const float* __restrict__ X, const float* __restrict__ R,
                const float* __restrict__ w, const float* __restrict__ b,
                float* __restrict__ Y, u16t* __restrict__ Yb)
{
    const int lane = threadIdx.x & 63, wid = threadIdx.x >> 6;
    const size_t row = (size_t)blockIdx.x * 4 + wid;
    const float* x = X + row * 512;
    const float* r = R + row * 512;
    const int c0 = lane * 8;
    float v[8];
    {
        const float4 a0 = *(const float4*)(x + c0);
        const float4 a1 = *(const float4*)(x + c0 + 4);
        const float4 r0 = *(const float4*)(r + c0);
        const float4 r1 = *(const float4*)(r + c0 + 4);
        v[0] = a0.x + r0.x; v[1] = a0.y + r0.y; v[2] = a0.z + r0.z; v[3] = a0.w + r0.w;
        v[4] = a1.x + r1.x; v[5] = a1.y + r1.y; v[6] = a1.z + r1.z; v[7] = a1.w + r1.w;
    }
    float s = 0.f;
#pragma unroll
    for (int j = 0; j < 8; ++j) s += v[j];
#pragma unroll
    for (int off = 1; off < 64; off <<= 1) s += __shfl_xor(s, off);
    const float mean = s * (1.f / 512.f);
    float q = 0.f;
#pragma unroll
    for (int j = 0; j < 8; ++j) { const float dd = v[j] - mean; q += dd * dd; }
#pragma unroll
    for (int off = 1; off < 64; off <<= 1) q += __shfl_xor(q, off);
    const float rstd = rsqrtf(q * (1.f / 512.f) + 1e-5f);
    float* y = Y + row * 512;
    u16t* yb = Yb + row * 512;
#pragma unroll
    for (int j = 0; j < 8; ++j) {
        const float o = (v[j] - mean) * rstd * w[c0 + j] + b[c0 + j];
        y[c0 + j] = o;
        yb[c0 + j] = f2b(o);
    }
}

// ---------------------------------------------------------------------------
// V transpose: Vt[b,h,d,l] (bf16) from QKVb[b,l,1024+h*128+d] (bf16).
// grid (L/64, B*H), block 256.
// ---------------------------------------------------------------------------
__global__ __launch_bounds__(256)
void vtprep(const u16t* __restrict__ QKVb, u16t* __restrict__ Vt)
{
    __shared__ u16t T[128 * 72];
    const int tid = threadIdx.x;
    const int l0 = blockIdx.x * 64;
    const int bh = blockIdx.y, b = bh >> 2, h = bh & 3;
#pragma unroll
    for (int it = 0; it < 4; ++it) {
        const int e = it * 256 + tid;
        const int l = e >> 4, dc = e & 15;
        const us8 v = *(const us8*)(QKVb + ((size_t)(b * 2048 + l0 + l)) * 1536
                                   + 1024 + h * 128 + dc * 8);
#pragma unroll
        for (int j = 0; j < 8; ++j) T[(dc * 8 + j) * 72 + l] = v[j];
    }
    __syncthreads();
#pragma unroll
    for (int it = 0; it < 4; ++it) {
        const int e = it * 256 + tid;
        const int d = e >> 3, lc = e & 7;
        const us8 ov = *(const us8*)&T[d * 72 + lc * 8];
        *(us8*)(Vt + ((size_t)bh * 128 + d) * 2048 + l0 + lc * 8) = ov;
    }
}

// ---------------------------------------------------------------------------
// MFMA flash attention. grid (L/64, B*H), 256 thr (4 waves x 16 q-rows).
// Q,K from QKVb [B,L,1536]; V from Vt [B,H,128,L]; out AOb bf16 [B,L,512].
// ---------------------------------------------------------------------------
__global__ __launch_bounds__(256)
void attn_bf16(const u16t* __restrict__ QKVb, const u16t* __restrict__ Vt,
               u16t* __restrict__ AOb)
{
    __shared__ u16t Kt[8192];    // [dblk 16][key 64][8]
    __shared__ u16t Vtl[8192];   // [kblk 8][d 128][8]
    __shared__ u16t Pl[4096];    // [wave 4][kblk 8][row 16][8]
    const int tid = threadIdx.x, lane = tid & 63, w = tid >> 6;
    const int l15 = lane & 15, l4 = lane >> 4;
    const int q0 = blockIdx.x * 64;
    const int bh = blockIdx.y, b = bh >> 2, h = bh & 3;
    const float SCALE = 0.08838834764831845f;   // 1/sqrt(128)

    s16x8 qf[4];
    {
        const u16t* qp = QKVb + ((size_t)(b * 2048 + q0 + w * 16 + l15)) * 1536
                         + h * 128 + l4 * 8;
#pragma unroll
        for (int ks = 0; ks < 4; ++ks) qf[ks] = *(const s16x8*)(qp + ks * 32);
    }
    f32x4 o[8];
#pragma unroll
    for (int i = 0; i < 8; ++i) o[i] = (f32x4){0.f, 0.f, 0.f, 0.f};
    f32x4 m_run, l_run;
#pragma unroll
    for (int r = 0; r < 4; ++r) { m_run[r] = -1e30f; l_run[r] = 0.f; }

    for (int kt = 0; kt < 32; ++kt) {
        const int k0 = kt * 64;
#pragma unroll
        for (int it = 0; it < 4; ++it) {
            const int e = it * 256 + tid, e0 = it * 256 + (tid & 192);
            const int dblk = e >> 6, key = e & 63;
            gload16(QKVb + ((size_t)(b * 2048 + k0 + key)) * 1536 + 512 + h * 128 + dblk * 8,
                    &Kt[(size_t)e0 * 8]);
        }
#pragma unroll
        for (int it = 0; it < 4; ++it) {
            const int e = it * 256 + tid, e0 = it * 256 + (tid & 192);
            const int kb = e >> 7, d = e & 127;
            gload16(Vt + ((size_t)bh * 128 + d) * 2048 + k0 + kb * 8,
                    &Vtl[(size_t)e0 * 8]);
        }
        __syncthreads();
        // QK^T
        f32x4 s[4];
#pragma unroll
        for (int ni = 0; ni < 4; ++ni) s[ni] = (f32x4){0.f, 0.f, 0.f, 0.f};
#pragma unroll
        for (int ks = 0; ks < 4; ++ks) {
#pragma unroll
            for (int ni = 0; ni < 4; ++ni) {
                const s16x8 kf = *(const s16x8*)&Kt[(size_t)((ks * 4 + l4) * 64 + ni * 16 + l15) * 8];
                s[ni] = __builtin_amdgcn_mfma_f32_16x16x32_bf16(qf[ks], kf, s[ni], 0, 0, 0);
            }
        }
        // online softmax (row r lives in the 16 lanes sharing l4)
        f32x4 mx;
#pragma unroll
        for (int r = 0; r < 4; ++r) {
            float t = fmaxf(fmaxf(s[0][r], s[1][r]), fmaxf(s[2][r], s[3][r]));
            mx[r] = t * SCALE;
        }
#pragma unroll
        for (int off = 1; off < 16; off <<= 1)
#pragma unroll
            for (int r = 0; r < 4; ++r) mx[r] = fmaxf(mx[r], __shfl_xor(mx[r], off));
        f32x4 nm, corr, rs;
#pragma unroll
        for (int r = 0; r < 4; ++r) {
            nm[r] = fmaxf(m_run[r], mx[r]);
            corr[r] = __expf(m_run[r] - nm[r]);
            rs[r] = 0.f;
        }
        float p[4][4];
#pragma unroll
        for (int ni = 0; ni < 4; ++ni)
#pragma unroll
            for (int r = 0; r < 4; ++r) {
                p[ni][r] = __expf(s[ni][r] * SCALE - nm[r]);
                rs[r] += p[ni][r];
            }
#pragma unroll
        for (int off = 1; off < 16; off <<= 1)
#pragma unroll
            for (int r = 0; r < 4; ++r) rs[r] += __shfl_xor(rs[r], off);
#pragma unroll
        for (int r = 0; r < 4; ++r) {
            l_run[r] = l_run[r] * corr[r] + rs[r];
            m_run[r] = nm[r];
        }
#pragma unroll
        for (int ni = 0; ni < 8; ++ni)
#pragma unroll
            for (int r = 0; r < 4; ++r) o[ni][r] *= corr[r];
        // P -> bf16 -> per-wave LDS ([kblk][row][8])
#pragma unroll
        for (int ni = 0; ni < 4; ++ni) {
            const int key = ni * 16 + l15;
            const int kb = key >> 3, kj = key & 7;
#pragma unroll
            for (int r = 0; r < 4; ++r)
                Pl[(size_t)((w * 8 + kb) * 16 + l4 * 4 + r) * 8 + kj] = f2b(p[ni][r]);
        }
        // PV
#pragma unroll
        for (int kk = 0; kk < 2; ++kk) {
            const s16x8 pa = *(const s16x8*)&Pl[(size_t)((w * 8 + kk * 4 + l4) * 16 + l15) * 8];
#pragma unroll
            for (int ni = 0; ni < 8; ++ni) {
                const s16x8 vf = *(const s16x8*)&Vtl[(size_t)((kk * 4 + l4) * 128 + ni * 16 + l15) * 8];
                o[ni] = __builtin_amdgcn_mfma_f32_16x16x32_bf16(pa, vf, o[ni], 0, 0, 0);
            }
        }
        __syncthreads();
    }
    f32x4 inv;
#pragma unroll
    for (int r = 0; r < 4; ++r) inv[r] = 1.f / l_run[r];
#pragma unroll
    for (int ni = 0; ni < 8; ++ni)
#pragma unroll
        for (int r = 0; r < 4; ++r)
            AOb[((size_t)(b * 2048 + q0 + w * 16 + l4 * 4 + r)) * 512
                + h * 128 + ni * 16 + l15] = f2b(o[ni][r] * inv[r]);
}

// ---------------------------------------------------------------------------
// concat -> padded bf16 [M,576]: cols 0..3 = ci, 4..515 = cd(bf16), rest 0
// ---------------------------------------------------------------------------
__global__ __launch_bounds__(256)
void concat_b(const float* __restrict__ CI, const u16t* __restrict__ Hb,
              u16t* __restrict__ OUTC)
{
    const size_t total = (size_t)16384 * 576;
    size_t i = (size_t)blockIdx.x * 256 + threadIdx.x;
    if (i >= total) return;
    const int col = (int)(i % 576);
    const size_t rowi = i / 576;
    u16t v = 0;
    if (col < 4) v = f2b(CI[rowi * 4 + col]);
    else if (col < 516) v = Hb[rowi * 512 + (col - 4)];
    OUTC[i] = v;
}

// ---------------------------------------------------------------------------
// fp32 -> bf16 converters
// ---------------------------------------------------------------------------
__global__ __launch_bounds__(256)
void cvt_plain(const float* __restrict__ src, u16t* __restrict__ dst, size_t n8)
{
    const size_t i = (size_t)blockIdx.x * 256 + threadIdx.x;
    if (i >= n8) return;
    const float4 a = ((const float4*)src)[i * 2];
    const float4 b = ((const float4*)src)[i * 2 + 1];
    us8 o;
    o[0] = f2b(a.x); o[1] = f2b(a.y); o[2] = f2b(a.z); o[3] = f2b(a.w);
    o[4] = f2b(b.x); o[5] = f2b(b.y); o[6] = f2b(b.z); o[7] = f2b(b.w);
    ((us8*)dst)[i] = o;
}

__global__ __launch_bounds__(256)
void cvt_pad(const float* __restrict__ src, u16t* __restrict__ dst,
             int rows, int sc, int dc)
{
    const size_t i = (size_t)blockIdx.x * 256 + threadIdx.x;
    const size_t total = (size_t)rows * dc;
    if (i >= total) return;
    const int c = (int)(i % dc);
    const size_t r = i / dc;
    dst[i] = (c < sc) ? f2b(src[r * sc + c]) : (u16t)0;
}

// ---------------------------------------------------------------------------
// final tiny GEMM: out[M,16] = T1[M,512] @ W2[16,512]^T + b2   (fp32)
// ---------------------------------------------------------------------------
__global__ __launch_bounds__(256)
void cls2_kernel(const float* __restrict__ T1, const float* __restrict__ W2,
                 const float* __restrict__ b2, float* __restrict__ out)
{
    const int t = threadIdx.x;
    const int r = blockIdx.x * 16 + (t >> 4), c = t & 15;
    const float4* a = (const float4*)(T1 + (size_t)r * 512);
    const float4* wv = (const float4*)(W2 + (size_t)c * 512);
    float acc = 0.f;
    for (int k = 0; k < 128; ++k) {
        const float4 x = a[k], y = wv[k];
        acc += x.x * y.x + x.y * y.y + x.z * y.z + x.w * y.w;
    }
    out[(size_t)r * 16 + c] = acc + b2[c];
}

// ---------------------------------------------------------------------------
extern "C" void kernel_launch(void* const* d_in, const int* in_sizes, int n_in,
                              void* d_out, int out_size, void* d_ws, size_t ws_size,
                              hipStream_t stream)
{
    (void)in_sizes; (void)n_in; (void)out_size; (void)ws_size;
    const int M = 16384;   // B*L

    const float* x        = (const float*)d_in[0];
    const float* spk_emb  = (const float*)d_in[1];
    const float* enc0_w   = (const float*)d_in[2];
    const float* enc0_b   = (const float*)d_in[3];
    const float* enc_lw   = (const float*)d_in[4];
    const float* enc_lb   = (const float*)d_in[5];
    const float* enc_mw   = (const float*)d_in[6];
    const float* enc_mb   = (const float*)d_in[7];
    const float* spk_w1   = (const float*)d_in[8];
    const float* spk_b1   = (const float*)d_in[9];
    const float* spk_w2   = (const float*)d_in[10];
    const float* spk_b2   = (const float*)d_in[11];
    const float* spk_w3   = (const float*)d_in[12];
    const float* spk_b3   = (const float*)d_in[13];
    const float* tr_in_w  = (const float*)d_in[14];
    const float* tr_in_b  = (const float*)d_in[15];
    const float* tr_out_w = (const float*)d_in[16];
    const float* tr_out_b = (const float*)d_in[17];
    const float* tr_ln1_w = (const float*)d_in[18];
    const float* tr_ln1_b = (const float*)d_in[19];
    const float* tr_ff1_w = (const float*)d_in[20];
    const float* tr_ff1_b = (const float*)d_in[21];
    const float* tr_ff2_w = (const float*)d_in[22];
    const float* tr_ff2_b = (const float*)d_in[23];
    const float* tr_ln2_w = (const float*)d_in[24];
    const float* tr_ln2_b = (const float*)d_in[25];
    const float* adpt_w   = (const float*)d_in[26];
    const float* adpt_b   = (const float*)d_in[27];
    const float* post_lw  = (const float*)d_in[28];
    const float* post_lb  = (const float*)d_in[29];
    const float* post_mw  = (const float*)d_in[30];
    const float* post_mb  = (const float*)d_in[31];
    const float* cls_w1   = (const float*)d_in[32];
    const float* cls_b1   = (const float*)d_in[33];
    const float* cls_w2   = (const float*)d_in[34];
    const float* cls_b2   = (const float*)d_in[35];

    // ---- workspace layout ----
    char* wsp = (char*)d_ws;
    size_t off = 0;
    auto alloc = [&](size_t bytes) -> void* {
        void* p = wsp + off; off += (bytes + 255) & ~(size_t)255; return p;
    };
    float* H    = (float*)alloc((size_t)M * 512 * 4);
    u16t*  Hb   = (u16t*) alloc((size_t)M * 512 * 2);
    float* T1   = (float*)alloc((size_t)M * 512 * 4);
    u16t*  Mb   = (u16t*) alloc((size_t)M * 512 * 2);   // also AOb
    u16t*  BIG  = (u16t*) alloc((size_t)M * 2048 * 2);  // QKVb+Vt | Fb | Xcatb
    float* CI   = (float*)alloc((size_t)M * 4 * 4);
    float* S3   = (float*)alloc(32 * 512 * 4);
    // bf16 weight/activation pool
    u16t* xb        = (u16t*)alloc((size_t)M * 128 * 2);
    u16t* enc0_wb   = (u16t*)alloc(512 * 128 * 2);
    u16t* enc_lwb   = (u16t*)alloc((size_t)8 * 512 * 512 * 2);
    u16t* enc_mwb   = (u16t*)alloc((size_t)8 * 512 * 512 * 2);
    u16t* spk_embb  = (u16t*)alloc(32 * 192 * 2);
    u16t* spk_w1b   = (u16t*)alloc(512 * 192 * 2);
    u16t* spk_w2b   = (u16t*)alloc(512 * 512 * 2);
    u16t* spk_w3b   = (u16t*)alloc(512 * 512 * 2);
    u16t* tr_in_wb  = (u16t*)alloc((size_t)4 * 1536 * 512 * 2);
    u16t* tr_out_wb = (u16t*)alloc((size_t)4 * 512 * 512 * 2);
    u16t* tr_ff1_wb = (u16t*)alloc((size_t)4 * 2048 * 512 * 2);
    u16t* tr_ff2_wb = (u16t*)alloc((size_t)4 * 2048 * 512 * 2);
    u16t* adpt_wb   = (u16t*)alloc(512 * 576 * 2);
    u16t* post_lwb  = (u16t*)alloc((size_t)6 * 512 * 512 * 2);
    u16t* post_mwb  = (u16t*)alloc((size_t)6 * 512 * 512 * 2);
    u16t* cls_w1b   = (u16t*)alloc(512 * 512 * 2);
    u16t* S1b       = (u16t*)alloc(32 * 512 * 2);
    u16t* S2b       = (u16t*)alloc(32 * 512 * 2);

    u16t* QKVb  = BIG;
    u16t* Vt    = BIG + (size_t)M * 1536;
    u16t* Fb    = BIG;
    u16t* Xcatb = BIG;
    u16t* AOb   = Mb;

    auto cplain = [&](const float* s, u16t* d, size_t n) {
        const size_t n8 = n / 8;
        cvt_plain<<<dim3((unsigned)((n8 + 255) / 256)), dim3(256), 0, stream>>>(s, d, n8);
    };
    auto cpad = [&](const float* s, u16t* d, int rows, int sc, int dc) {
        const size_t tot = (size_t)rows * dc;
        cvt_pad<<<dim3((unsigned)((tot + 255) / 256)), dim3(256), 0, stream>>>(s, d, rows, sc, dc);
    };
    auto gemm = [&](const u16t* A, int lda, const u16t* W, int ldw,
                    const float* bias, const float* R, float* C, u16t* Cb,
                    int m, int n, int k, int flags) {
        dim3 g(n / 128, (m + 127) / 128);
        gemm_bf16<<<g, dim3(256), 0, stream>>>(A, lda, W, ldw, bias, R, C, Cb, m, n, k, flags);
    };

    // --- weight & input conversion ---
    cpad(x, xb, M, 80, 128);
    cpad(enc0_w, enc0_wb, 512, 80, 128);
    cplain(enc_lw, enc_lwb, (size_t)8 * 512 * 512);
    cplain(enc_mw, enc_mwb, (size_t)8 * 512 * 512);
    cplain(spk_emb, spk_embb, 32 * 192);
    cplain(spk_w1, spk_w1b, 512 * 192);
    cplain(spk_w2, spk_w2b, 512 * 512);
    cplain(spk_w3, spk_w3b, 512 * 512);
    cplain(tr_in_w, tr_in_wb, (size_t)4 * 1536 * 512);
    cplain(tr_out_w, tr_out_wb, (size_t)4 * 512 * 512);
    cplain(tr_ff1_w, tr_ff1_wb, (size_t)4 * 2048 * 512);
    cplain(tr_ff2_w, tr_ff2_wb, (size_t)4 * 2048 * 512);
    cpad(adpt_w, adpt_wb, 512, 516, 576);
    cplain(post_lw, post_lwb, (size_t)6 * 512 * 512);
    cplain(post_mw, post_mwb, (size_t)6 * 512 * 512);
    cplain(cls_w1, cls_w1b, 512 * 512);

    // --- encoder ---
    gemm(xb, 128, enc0_wb, 128, enc0_b, nullptr, nullptr, Hb, M, 512, 128, GB_WB16);
    for (int i = 0; i < 8; ++i) {
        gemm(Hb, 512, enc_lwb + (size_t)i * 262144, 512, enc_lb + (size_t)i * 512,
             nullptr, T1, nullptr, M, 512, 512, GB_WF32);
        fsmn_means_b<<<dim3(2, 8, 8), dim3(256), 0, stream>>>(Hb, Mb, 1 << i);
        const int fl = GB_RES | GB_WB16 | (i == 7 ? GB_WF32 : 0);
        gemm(Mb, 512, enc_mwb + (size_t)i * 262144, 512, enc_mb + (size_t)i * 512,
             T1, H, Hb, M, 512, 512, fl);
    }

    // --- speaker MLP ---
    gemm(spk_embb, 192, spk_w1b, 192, spk_b1, nullptr, nullptr, S1b, 32, 512, 192, GB_RELU | GB_WB16);
    gemm(S1b, 512, spk_w2b, 512, spk_b2, nullptr, nullptr, S2b, 32, 512, 512, GB_RELU | GB_WB16);
    gemm(S2b, 512, spk_w3b, 512, spk_b3, nullptr, S3, nullptr, 32, 512, 512, GB_WF32);

    // --- context-independent scores (from encoder Hb) ---
    ci_kernel<<<dim3(65536 / 256), dim3(256), 0, stream>>>(Hb, S3, CI);

    // --- transformer ---
    for (int i = 0; i < 4; ++i) {
        gemm(Hb, 512, tr_in_wb + (size_t)i * 786432, 512, tr_in_b + (size_t)i * 1536,
             nullptr, nullptr, QKVb, M, 1536, 512, GB_WB16);
        vtprep<<<dim3(32, 32), dim3(256), 0, stream>>>(QKVb, Vt);
        attn_bf16<<<dim3(32, 32), dim3(256), 0, stream>>>(QKVb, Vt, AOb);
        gemm(AOb, 512, tr_out_wb + (size_t)i * 262144, 512, tr_out_b + (size_t)i * 512,
             nullptr, T1, nullptr, M, 512, 512, GB_WF32);
        ln_add_f32<<<dim3(M / 4), dim3(256), 0, stream>>>(
            H, T1, tr_ln1_w + (size_t)i * 512, tr_ln1_b + (size_t)i * 512, H, Hb);
        gemm(Hb, 512, tr_ff1_wb + (size_t)i * 1048576, 512, tr_ff1_b + (size_t)i * 2048,
             nullptr, nullptr, Fb, M, 2048, 512, GB_RELU | GB_WB16);
        gemm(Fb, 2048, tr_ff2_wb + (size_t)i * 1048576, 2048, tr_ff2_b + (size_t)i * 512,
             nullptr, T1, nullptr, M, 512, 2048, GB_WF32);
        ln_add_f32<<<dim3(M / 4), dim3(256), 0, stream>>>(
            H, T1, tr_ln2_w + (size_t)i * 512, tr_ln2_b + (size_t)i * 512, H, Hb);
    }

    // --- concat + adapter ---
    concat_b<<<dim3((unsigned)(((size_t)M * 576 + 255) / 256)), dim3(256), 0, stream>>>(CI, Hb, Xcatb);
    gemm(Xcatb, 576, adpt_wb, 576, adpt_b, nullptr, nullptr, Hb, M, 512, 576, GB_WB16);

    // --- post FSMN ---
    for (int i = 0; i < 6; ++i) {
        gemm(Hb, 512, post_lwb + (size_t)i * 262144, 512, post_lb + (size_t)i * 512,
             nullptr, T1, nullptr, M, 512, 512, GB_WF32);
        fsmn_means_b<<<dim3(2, 8, 8), dim3(256), 0, stream>>>(Hb, Mb, 1 << i);
        gemm(Mb, 512, post_mwb + (size_t)i * 262144, 512, post_mb + (size_t)i * 512,
             T1, nullptr, Hb, M, 512, 512, GB_RES | GB_WB16);
    }

    // --- classifier ---
    gemm(Hb, 512, cls_w1b, 512, cls_b1, nullptr, T1, nullptr, M, 512, 512, GB_RELU | GB_WF32);
    cls2_kernel<<<dim3(M / 16), dim3(256), 0, stream>>>(T1, cls_w2, cls_b2, (float*)d_out);
}

// Round 5
// 4691.501 us; speedup vs baseline: 3.6243x; 1.2723x over previous
//
#include <hip/hip_runtime.h>
#include <hip/hip_bf16.h>
#include <math.h>

typedef unsigned short u16t;
using f32x4 = __attribute__((ext_vector_type(4))) float;
using s16x8 = __attribute__((ext_vector_type(8))) short;
using us8   = __attribute__((ext_vector_type(8))) unsigned short;

#define GB_RELU 1
#define GB_RES  2
#define GB_WF32 4
#define GB_WB16 8

__device__ __forceinline__ u16t f2b(float f) {
    unsigned u = __float_as_uint(f);
    unsigned r = (u + 0x7FFFu + ((u >> 16) & 1u)) >> 16;
    return (u16t)r;
}
__device__ __forceinline__ float b2f(u16t s) {
    return __uint_as_float(((unsigned)s) << 16);
}
__device__ __forceinline__ void gload16(const void* gsrc, void* ldst) {
    __builtin_amdgcn_global_load_lds(
        (const __attribute__((address_space(1))) void*)gsrc,
        (__attribute__((address_space(3))) void*)ldst, 16, 0, 0);
}

// ---------------------------------------------------------------------------
// bf16 MFMA GEMM, 2-phase pipelined (counted vmcnt, raw barriers), swizzled LDS.
// C[M,N] = A[M,K](bf16) @ W[N,K]^T(bf16) + bias + R, relu opt.
// 128x128 tile, BK=64, 256 thr (4 waves 2x2). K%64==0, N%128==0, M arbitrary.
// LDS unit (kb,row) holds global row (row ^ (kb&3)); reads use l15^l4.
// ---------------------------------------------------------------------------
__global__ __launch_bounds__(256)
void gemm_bf16(const u16t* __restrict__ A, int lda,
               const u16t* __restrict__ W, int ldw,
               const float* __restrict__ bias, const float* __restrict__ R,
               float* __restrict__ C, u16t* __restrict__ Cb,
               int M, int N, int K, int flags)
{
    __shared__ u16t As[2][8192];
    __shared__ u16t Ws[2][8192];
    const int tid = threadIdx.x;
    const int lane = tid & 63, w = tid >> 6;
    const int wr = w >> 1, wc = w & 1;
    const int l15 = lane & 15, l4 = lane >> 4;
    const int m0 = blockIdx.y * 128, n0 = blockIdx.x * 128;

    int arow[4], wrow[4], koff[4], se0[4];
#pragma unroll
    for (int it = 0; it < 4; ++it) {
        const int e = it * 256 + tid;
        se0[it] = it * 256 + (tid & 192);
        const int kb = e >> 7, r = e & 127;
        const int rg = r ^ (kb & 3);
        int gm = m0 + rg; if (gm > M - 1) gm = M - 1;
        arow[it] = gm;
        wrow[it] = n0 + rg;
        koff[it] = kb * 8;
    }

    f32x4 acc[4][4];
#pragma unroll
    for (int i = 0; i < 4; ++i)
#pragma unroll
        for (int j = 0; j < 4; ++j) acc[i][j] = (f32x4){0.f, 0.f, 0.f, 0.f};

    auto STAGE = [&](int buf, int k0) {
#pragma unroll
        for (int it = 0; it < 4; ++it)
            gload16(A + (size_t)arow[it] * lda + k0 + koff[it],
                    &As[buf][(size_t)se0[it] * 8]);
#pragma unroll
        for (int it = 0; it < 4; ++it)
            gload16(W + (size_t)wrow[it] * ldw + k0 + koff[it],
                    &Ws[buf][(size_t)se0[it] * 8]);
    };

    const int nk = K >> 6;
    STAGE(0, 0);
    for (int ks = 0; ks < nk; ++ks) {
        const int cur = ks & 1;
        if (ks + 1 < nk) {
            STAGE(cur ^ 1, (ks + 1) << 6);
            asm volatile("s_waitcnt vmcnt(8)" ::: "memory");
        } else {
            asm volatile("s_waitcnt vmcnt(0)" ::: "memory");
        }
        __builtin_amdgcn_s_barrier();
#pragma unroll
        for (int kk = 0; kk < 2; ++kk) {
            const int kb = kk * 4 + l4;
            const int ls = l15 ^ l4;     // swizzled row-within-16 on read
            s16x8 a[4], b[4];
#pragma unroll
            for (int mi = 0; mi < 4; ++mi)
                a[mi] = *(const s16x8*)&As[cur][(size_t)(kb * 128 + wr * 64 + mi * 16 + ls) * 8];
#pragma unroll
            for (int ni = 0; ni < 4; ++ni)
                b[ni] = *(const s16x8*)&Ws[cur][(size_t)(kb * 128 + wc * 64 + ni * 16 + ls) * 8];
#pragma unroll
            for (int mi = 0; mi < 4; ++mi)
#pragma unroll
                for (int ni = 0; ni < 4; ++ni)
                    acc[mi][ni] = __builtin_amdgcn_mfma_f32_16x16x32_bf16(
                        a[mi], b[ni], acc[mi][ni], 0, 0, 0);
        }
        __builtin_amdgcn_s_barrier();
    }

#pragma unroll
    for (int mi = 0; mi < 4; ++mi) {
#pragma unroll
        for (int r = 0; r < 4; ++r) {
            const int row = m0 + wr * 64 + mi * 16 + l4 * 4 + r;
            if (row >= M) continue;
#pragma unroll
            for (int ni = 0; ni < 4; ++ni) {
                const int col = n0 + wc * 64 + ni * 16 + l15;
                float v = acc[mi][ni][r];
                if (bias) v += bias[col];
                if (flags & GB_RES) v += R[(size_t)row * N + col];
                if (flags & GB_RELU) v = fmaxf(v, 0.f);
                if (flags & GB_WF32) C[(size_t)row * N + col] = v;
                if (flags & GB_WB16) Cb[(size_t)row * N + col] = f2b(v);
            }
        }
    }
}

// ---------------------------------------------------------------------------
// FSMN sliding-window mean on bf16 activations (fp32 running sum).
// grid (2, 16, 8) = (D/256, L/128, B), block 256, chunk 128.
// ---------------------------------------------------------------------------
__global__ __launch_bounds__(256)
void fsmn_means_b(const u16t* __restrict__ Hb, u16t* __restrict__ Mb, int stride)
{
    const int d = blockIdx.x * 256 + threadIdx.x;
    const int b = blockIdx.z;
    const int c0 = blockIdx.y * 128;
    const u16t* Hp = Hb + (size_t)b * 2048 * 512 + d;
    u16t* Mp = Mb + (size_t)b * 2048 * 512 + d;
    float sum = 0.f;
    int s0 = c0 - stride; if (s0 < 0) s0 = 0;
    for (int j = s0; j < c0; ++j) sum += b2f(Hp[(size_t)j * 512]);
    for (int i = c0; i < c0 + 128; ++i) {
        sum += b2f(Hp[(size_t)i * 512]);
        const int st = i - stride;
        const float cnt = (float)(i + 1 - (st > 0 ? st : 0));
        Mp[(size_t)i * 512] = f2b(sum / cnt);
        if (st >= 0) sum -= b2f(Hp[(size_t)st * 512]);
    }
}

// ---------------------------------------------------------------------------
// ci[b,l,s] = dot(Hb[b,l,:], SF[b,s,:])
// ---------------------------------------------------------------------------
__global__ __launch_bounds__(256)
void ci_kernel(const u16t* __restrict__ Hb, const float* __restrict__ SF,
               float* __restrict__ CI)
{
    const int idx = blockIdx.x * 256 + threadIdx.x;   // 65536
    const int s = idx & 3;
    const int bl = idx >> 2;
    const int b = bl >> 11;
    const us8* h8 = (const us8*)(Hb + (size_t)bl * 512);
    const float4* f4 = (const float4*)(SF + ((size_t)(b * 4 + s)) * 512);
    float acc = 0.f;
    for (int k = 0; k < 64; ++k) {
        const us8 hv = h8[k];
        const float4 f0 = f4[k * 2], f1 = f4[k * 2 + 1];
        acc += b2f(hv[0]) * f0.x + b2f(hv[1]) * f0.y + b2f(hv[2]) * f0.z + b2f(hv[3]) * f0.w
             + b2f(hv[4]) * f1.x + b2f(hv[5]) * f1.y + b2f(hv[6]) * f1.z + b2f(hv[7]) * f1.w;
    }
    CI[idx] = acc;
}

// ---------------------------------------------------------------------------
// Y = LN(X + R) * w + b ; writes fp32 Y and bf16 Yb. One wave per row.
// ---------------------------------------------------------------------------
__global__ __launch_bounds__(256)
void ln_add_f32(const float* __restrict__ X, const float* __restrict__ R,
                const float* __restrict__ w, const float* __restrict__ b,
                float* __restrict__ Y, u16t* __restrict__ Yb)
{
    const int lane = threadIdx.x & 63, wid = threadIdx.x >> 6;
    const size_t row = (size_t)blockIdx.x * 4 + wid;
    const float* x = X + row * 512;
    const float* r = R + row * 512;
    const int c0 = lane * 8;
    float v[8];
    {
        const float4 a0 = *(const float4*)(x + c0);
        const float4 a1 = *(const float4*)(x + c0 + 4);
        const float4 r0 = *(const float4*)(r + c0);
        const float4 r1 = *(const float4*)(r + c0 + 4);
        v[0] = a0.x + r0.x; v[1] = a0.y + r0.y; v[2] = a0.z + r0.z; v[3] = a0.w + r0.w;
        v[4] = a1.x + r1.x; v[5] = a1.y + r1.y; v[6] = a1.z + r1.z; v[7] = a1.w + r1.w;
    }
    float s = 0.f;
#pragma unroll
    for (int j = 0; j < 8; ++j) s += v[j];
#pragma unroll
    for (int off = 1; off < 64; off <<= 1) s += __shfl_xor(s, off);
    const float mean = s * (1.f / 512.f);
    float q = 0.f;
#pragma unroll
    for (int j = 0; j < 8; ++j) { const float dd = v[j] - mean; q += dd * dd; }
#pragma unroll
    for (int off = 1; off < 64; off <<= 1) q += __shfl_xor(q, off);
    const float rstd = rsqrtf(q * (1.f / 512.f) + 1e-5f);
    float* y = Y + row * 512;
    u16t* yb = Yb + row * 512;
#pragma unroll
    for (int j = 0; j < 8; ++j) {
        const float o = (v[j] - mean) * rstd * w[c0 + j] + b[c0 + j];
        y[c0 + j] = o;
        yb[c0 + j] = f2b(o);
    }
}

// ---------------------------------------------------------------------------
// V transpose: Vt[b,h,d,l] (bf16) from QKVb[b,l,1024+h*128+d] (bf16).
// grid (L/64, B*H), block 256.
// ---------------------------------------------------------------------------
__global__ __launch_bounds__(256)
void vtprep(const u16t* __restrict__ QKVb, u16t* __restrict__ Vt)
{
    __shared__ u16t T[128 * 72];
    const int tid = threadIdx.x;
    const int l0 = blockIdx.x * 64;
    const int bh = blockIdx.y, b = bh >> 2, h = bh & 3;
#pragma unroll
    for (int it = 0; it < 4; ++it) {
        const int e = it * 256 + tid;
        const int l = e >> 4, dc = e & 15;
        const us8 v = *(const us8*)(QKVb + ((size_t)(b * 2048 + l0 + l)) * 1536
                                   + 1024 + h * 128 + dc * 8);
#pragma unroll
        for (int j = 0; j < 8; ++j) T[(dc * 8 + j) * 72 + l] = v[j];
    }
    __syncthreads();
#pragma unroll
    for (int it = 0; it < 4; ++it) {
        const int e = it * 256 + tid;
        const int d = e >> 3, lc = e & 7;
        const us8 ov = *(const us8*)&T[d * 72 + lc * 8];
        *(us8*)(Vt + ((size_t)bh * 128 + d) * 2048 + l0 + lc * 8) = ov;
    }
}

// ---------------------------------------------------------------------------
// MFMA flash attention, 2-phase pipelined. grid (L/128, B*H), 512 thr
// (8 waves x 16 q-rows). Q,K from QKVb [B,L,1536]; V from Vt [B,H,128,L].
// Per-lane l accumulation; defer-max THR=8; swizzled K/V LDS.
// ---------------------------------------------------------------------------
__global__ __launch_bounds__(512)
void attn_bf16(const u16t* __restrict__ QKVb, const u16t* __restrict__ Vt,
               u16t* __restrict__ AOb)
{
    __shared__ u16t Kt[2][8192];    // [dblk 16][key 64][8], key swizzled
    __shared__ u16t Vtl[2][8192];   // [kb 8][d 128][8], d swizzled
    __shared__ u16t Pl[8192];       // [wave 8][kb 8][row 16][8]
    const int tid = threadIdx.x, lane = tid & 63, w = tid >> 6;
    const int l15 = lane & 15, l4 = lane >> 4;
    const int q0 = blockIdx.x * 128;
    const int bh = blockIdx.y, b = bh >> 2, h = bh & 3;
    const float SCALE = 0.08838834764831845f;   // 1/sqrt(128)

    int krow[2], kdoff[2], vd[2], vkoff[2], se0[2];
#pragma unroll
    for (int it = 0; it < 2; ++it) {
        const int e = it * 512 + tid;
        se0[it] = it * 512 + (tid & 448);
        const int dblk = e >> 6, key = e & 63;
        krow[it] = key ^ (dblk & 3);
        kdoff[it] = dblk * 8;
        const int kb = e >> 7, d = e & 127;
        vd[it] = d ^ (kb & 3);
        vkoff[it] = kb * 8;
    }
    auto STAGE = [&](int buf, int k0) {
#pragma unroll
        for (int it = 0; it < 2; ++it)
            gload16(QKVb + ((size_t)(b * 2048 + k0 + krow[it])) * 1536 + 512 + h * 128 + kdoff[it],
                    &Kt[buf][(size_t)se0[it] * 8]);
#pragma unroll
        for (int it = 0; it < 2; ++it)
            gload16(Vt + ((size_t)bh * 128 + vd[it]) * 2048 + k0 + vkoff[it],
                    &Vtl[buf][(size_t)se0[it] * 8]);
    };

    s16x8 qf[4];
    {
        const u16t* qp = QKVb + ((size_t)(b * 2048 + q0 + w * 16 + l15)) * 1536
                         + h * 128 + l4 * 8;
#pragma unroll
        for (int ks = 0; ks < 4; ++ks) qf[ks] = *(const s16x8*)(qp + ks * 32);
    }
    asm volatile("s_waitcnt vmcnt(0)" ::: "memory");

    f32x4 o[8];
#pragma unroll
    for (int i = 0; i < 8; ++i) o[i] = (f32x4){0.f, 0.f, 0.f, 0.f};
    f32x4 m_run, lsum;
#pragma unroll
    for (int r = 0; r < 4; ++r) { m_run[r] = -1e30f; lsum[r] = 0.f; }

    const int ls = l15 ^ l4;
    STAGE(0, 0);
    for (int kt = 0; kt < 32; ++kt) {
        const int cur = kt & 1;
        if (kt + 1 < 32) {
            STAGE(cur ^ 1, (kt + 1) * 64);
            asm volatile("s_waitcnt vmcnt(4)" ::: "memory");
        } else {
            asm volatile("s_waitcnt vmcnt(0)" ::: "memory");
        }
        __builtin_amdgcn_s_barrier();

        // QK^T
        f32x4 s[4];
#pragma unroll
        for (int ni = 0; ni < 4; ++ni) s[ni] = (f32x4){0.f, 0.f, 0.f, 0.f};
#pragma unroll
        for (int ks = 0; ks < 4; ++ks) {
#pragma unroll
            for (int ni = 0; ni < 4; ++ni) {
                const s16x8 kf = *(const s16x8*)&Kt[cur][(size_t)((ks * 4 + l4) * 64 + ni * 16 + ls) * 8];
                s[ni] = __builtin_amdgcn_mfma_f32_16x16x32_bf16(qf[ks], kf, s[ni], 0, 0, 0);
            }
        }
        // row max over this tile (16 lanes share a row)
        f32x4 mx;
#pragma unroll
        for (int r = 0; r < 4; ++r)
            mx[r] = fmaxf(fmaxf(s[0][r], s[1][r]), fmaxf(s[2][r], s[3][r])) * SCALE;
#pragma unroll
        for (int off = 1; off < 16; off <<= 1)
#pragma unroll
            for (int r = 0; r < 4; ++r) mx[r] = fmaxf(mx[r], __shfl_xor(mx[r], off));
        // defer-max: only rescale when max grew by > 8
        bool small = true;
#pragma unroll
        for (int r = 0; r < 4; ++r) small = small && (mx[r] <= m_run[r] + 8.f);
        if (!__all(small)) {
            f32x4 corr;
#pragma unroll
            for (int r = 0; r < 4; ++r) {
                const float nm = fmaxf(m_run[r], mx[r]);
                corr[r] = __expf(m_run[r] - nm);
                m_run[r] = nm;
                lsum[r] *= corr[r];
            }
#pragma unroll
            for (int ni = 0; ni < 8; ++ni)
#pragma unroll
                for (int r = 0; r < 4; ++r) o[ni][r] *= corr[r];
        }
        float p[4][4];
#pragma unroll
        for (int ni = 0; ni < 4; ++ni)
#pragma unroll
            for (int r = 0; r < 4; ++r) {
                p[ni][r] = __expf(s[ni][r] * SCALE - m_run[r]);
                lsum[r] += p[ni][r];
            }
        // P -> bf16 -> per-wave LDS ([kb][row][8])
#pragma unroll
        for (int ni = 0; ni < 4; ++ni) {
            const int key = ni * 16 + l15;
            const int kb = key >> 3, kj = key & 7;
#pragma unroll
            for (int r = 0; r < 4; ++r)
                Pl[(size_t)((w * 8 + kb) * 16 + l4 * 4 + r) * 8 + kj] = f2b(p[ni][r]);
        }
        // PV
#pragma unroll
        for (int kk = 0; kk < 2; ++kk) {
            const s16x8 pa = *(const s16x8*)&Pl[(size_t)((w * 8 + kk * 4 + l4) * 16 + l15) * 8];
#pragma unroll
            for (int ni = 0; ni < 8; ++ni) {
                const s16x8 vf = *(const s16x8*)&Vtl[cur][(size_t)((kk * 4 + l4) * 128 + ni * 16 + ls) * 8];
                o[ni] = __builtin_amdgcn_mfma_f32_16x16x32_bf16(pa, vf, o[ni], 0, 0, 0);
            }
        }
        __builtin_amdgcn_s_barrier();
    }
    // final: reduce per-lane partial sums across the 16 lanes of each row
#pragma unroll
    for (int off = 1; off < 16; off <<= 1)
#pragma unroll
        for (int r = 0; r < 4; ++r) lsum[r] += __shfl_xor(lsum[r], off);
    f32x4 inv;
#pragma unroll
    for (int r = 0; r < 4; ++r) inv[r] = 1.f / lsum[r];
#pragma unroll
    for (int ni = 0; ni < 8; ++ni)
#pragma unroll
        for (int r = 0; r < 4; ++r)
            AOb[((size_t)(b * 2048 + q0 + w * 16 + l4 * 4 + r)) * 512
                + h * 128 + ni * 16 + l15] = f2b(o[ni][r] * inv[r]);
}

// ---------------------------------------------------------------------------
// concat -> padded bf16 [M,576]: cols 0..3 = ci, 4..515 = cd(bf16), rest 0
// ---------------------------------------------------------------------------
__global__ __launch_bounds__(256)
void concat_b(const float* __restrict__ CI, const u16t* __restrict__ Hb,
              u16t* __restrict__ OUTC)
{
    const size_t total = (size_t)16384 * 576;
    size_t i = (size_t)blockIdx.x * 256 + threadIdx.x;
    if (i >= total) return;
    const int col = (int)(i % 576);
    const size_t rowi = i / 576;
    u16t v = 0;
    if (col < 4) v = f2b(CI[rowi * 4 + col]);
    else if (col < 516) v = Hb[rowi * 512 + (col - 4)];
    OUTC[i] = v;
}

// ---------------------------------------------------------------------------
// fp32 -> bf16 converters
// ---------------------------------------------------------------------------
__global__ __launch_bounds__(256)
void cvt_plain(const float* __restrict__ src, u16t* __restrict__ dst, size_t n8)
{
    const size_t i = (size_t)blockIdx.x * 256 + threadIdx.x;
    if (i >= n8) return;
    const float4 a = ((const float4*)src)[i * 2];
    const float4 b = ((const float4*)src)[i * 2 + 1];
    us8 o;
    o[0] = f2b(a.x); o[1] = f2b(a.y); o[2] = f2b(a.z); o[3] = f2b(a.w);
    o[4] = f2b(b.x); o[5] = f2b(b.y); o[6] = f2b(b.z); o[7] = f2b(b.w);
    ((us8*)dst)[i] = o;
}

__global__ __launch_bounds__(256)
void cvt_pad(const float* __restrict__ src, u16t* __restrict__ dst,
             int rows, int sc, int dc)
{
    const size_t i = (size_t)blockIdx.x * 256 + threadIdx.x;
    const size_t total = (size_t)rows * dc;
    if (i >= total) return;
    const int c = (int)(i % dc);
    const size_t r = i / dc;
    dst[i] = (c < sc) ? f2b(src[r * sc + c]) : (u16t)0;
}

// ---------------------------------------------------------------------------
// final tiny GEMM: out[M,16] = T1[M,512] @ W2[16,512]^T + b2   (fp32)
// ---------------------------------------------------------------------------
__global__ __launch_bounds__(256)
void cls2_kernel(const float* __restrict__ T1, const float* __restrict__ W2,
                 const float* __restrict__ b2, float* __restrict__ out)
{
    const int t = threadIdx.x;
    const int r = blockIdx.x * 16 + (t >> 4), c = t & 15;
    const float4* a = (const float4*)(T1 + (size_t)r * 512);
    const float4* wv = (const float4*)(W2 + (size_t)c * 512);
    float acc = 0.f;
    for (int k = 0; k < 128; ++k) {
        const float4 x = a[k], y = wv[k];
        acc += x.x * y.x + x.y * y.y + x.z * y.z + x.w * y.w;
    }
    out[(size_t)r * 16 + c] = acc + b2[c];
}

// ---------------------------------------------------------------------------
extern "C" void kernel_launch(void* const* d_in, const int* in_sizes, int n_in,
                              void* d_out, int out_size, void* d_ws, size_t ws_size,
                              hipStream_t stream)
{
    (void)in_sizes; (void)n_in; (void)out_size; (void)ws_size;
    const int M = 16384;   // B*L

    const float* x        = (const float*)d_in[0];
    const float* spk_emb  = (const float*)d_in[1];
    const float* enc0_w   = (const float*)d_in[2];
    const float* enc0_b   = (const float*)d_in[3];
    const float* enc_lw   = (const float*)d_in[4];
    const float* enc_lb   = (const float*)d_in[5];
    const float* enc_mw   = (const float*)d_in[6];
    const float* enc_mb   = (const float*)d_in[7];
    const float* spk_w1   = (const float*)d_in[8];
    const float* spk_b1   = (const float*)d_in[9];
    const float* spk_w2   = (const float*)d_in[10];
    const float* spk_b2   = (const float*)d_in[11];
    const float* spk_w3   = (const float*)d_in[12];
    const float* spk_b3   = (const float*)d_in[13];
    const float* tr_in_w  = (const float*)d_in[14];
    const float* tr_in_b  = (const float*)d_in[15];
    const float* tr_out_w = (const float*)d_in[16];
    const float* tr_out_b = (const float*)d_in[17];
    const float* tr_ln1_w = (const float*)d_in[18];
    const float* tr_ln1_b = (const float*)d_in[19];
    const float* tr_ff1_w = (const float*)d_in[20];
    const float* tr_ff1_b = (const float*)d_in[21];
    const float* tr_ff2_w = (const float*)d_in[22];
    const float* tr_ff2_b = (const float*)d_in[23];
    const float* tr_ln2_w = (const float*)d_in[24];
    const float* tr_ln2_b = (const float*)d_in[25];
    const float* adpt_w   = (const float*)d_in[26];
    const float* adpt_b   = (const float*)d_in[27];
    const float* post_lw  = (const float*)d_in[28];
    const float* post_lb  = (const float*)d_in[29];
    const float* post_mw  = (const float*)d_in[30];
    const float* post_mb  = (const float*)d_in[31];
    const float* cls_w1   = (const float*)d_in[32];
    const float* cls_b1   = (const float*)d_in[33];
    const float* cls_w2   = (const float*)d_in[34];
    const float* cls_b2   = (const float*)d_in[35];

    // ---- workspace layout ----
    char* wsp = (char*)d_ws;
    size_t off = 0;
    auto alloc = [&](size_t bytes) -> void* {
        void* p = wsp + off; off += (bytes + 255) & ~(size_t)255; return p;
    };
    float* H    = (float*)alloc((size_t)M * 512 * 4);
    u16t*  Hb   = (u16t*) alloc((size_t)M * 512 * 2);
    float* T1   = (float*)alloc((size_t)M * 512 * 4);
    u16t*  Mb   = (u16t*) alloc((size_t)M * 512 * 2);   // also AOb
    u16t*  BIG  = (u16t*) alloc((size_t)M * 2048 * 2);  // QKVb+Vt | Fb | Xcatb
    float* CI   = (float*)alloc((size_t)M * 4 * 4);
    float* S3   = (float*)alloc(32 * 512 * 4);
    // bf16 weight/activation pool
    u16t* xb        = (u16t*)alloc((size_t)M * 128 * 2);
    u16t* enc0_wb   = (u16t*)alloc(512 * 128 * 2);
    u16t* enc_lwb   = (u16t*)alloc((size_t)8 * 512 * 512 * 2);
    u16t* enc_mwb   = (u16t*)alloc((size_t)8 * 512 * 512 * 2);
    u16t* spk_embb  = (u16t*)alloc(32 * 192 * 2);
    u16t* spk_w1b   = (u16t*)alloc(512 * 192 * 2);
    u16t* spk_w2b   = (u16t*)alloc(512 * 512 * 2);
    u16t* spk_w3b   = (u16t*)alloc(512 * 512 * 2);
    u16t* tr_in_wb  = (u16t*)alloc((size_t)4 * 1536 * 512 * 2);
    u16t* tr_out_wb = (u16t*)alloc((size_t)4 * 512 * 512 * 2);
    u16t* tr_ff1_wb = (u16t*)alloc((size_t)4 * 2048 * 512 * 2);
    u16t* tr_ff2_wb = (u16t*)alloc((size_t)4 * 2048 * 512 * 2);
    u16t* adpt_wb   = (u16t*)alloc(512 * 576 * 2);
    u16t* post_lwb  = (u16t*)alloc((size_t)6 * 512 * 512 * 2);
    u16t* post_mwb  = (u16t*)alloc((size_t)6 * 512 * 512 * 2);
    u16t* cls_w1b   = (u16t*)alloc(512 * 512 * 2);
    u16t* S1b       = (u16t*)alloc(32 * 512 * 2);
    u16t* S2b       = (u16t*)alloc(32 * 512 * 2);

    u16t* QKVb  = BIG;
    u16t* Vt    = BIG + (size_t)M * 1536;
    u16t* Fb    = BIG;
    u16t* Xcatb = BIG;
    u16t* AOb   = Mb;

    auto cplain = [&](const float* s, u16t* d, size_t n) {
        const size_t n8 = n / 8;
        cvt_plain<<<dim3((unsigned)((n8 + 255) / 256)), dim3(256), 0, stream>>>(s, d, n8);
    };
    auto cpad = [&](const float* s, u16t* d, int rows, int sc, int dc) {
        const size_t tot = (size_t)rows * dc;
        cvt_pad<<<dim3((unsigned)((tot + 255) / 256)), dim3(256), 0, stream>>>(s, d, rows, sc, dc);
    };
    // 12 params: A, lda, W, ldw, bias, R, C, Cb, m, n, k, flags
    auto gemm = [&](const u16t* A, int lda, const u16t* W, int ldw,
                    const float* bias, const float* R, float* C, u16t* Cb,
                    int m, int n, int k, int flags) {
        dim3 g(n / 128, (m + 127) / 128);
        gemm_bf16<<<g, dim3(256), 0, stream>>>(A, lda, W, ldw, bias, R, C, Cb, m, n, k, flags);
    };

    // --- weight & input conversion ---
    cpad(x, xb, M, 80, 128);
    cpad(enc0_w, enc0_wb, 512, 80, 128);
    cplain(enc_lw, enc_lwb, (size_t)8 * 512 * 512);
    cplain(enc_mw, enc_mwb, (size_t)8 * 512 * 512);
    cplain(spk_emb, spk_embb, 32 * 192);
    cplain(spk_w1, spk_w1b, 512 * 192);
    cplain(spk_w2, spk_w2b, 512 * 512);
    cplain(spk_w3, spk_w3b, 512 * 512);
    cplain(tr_in_w, tr_in_wb, (size_t)4 * 1536 * 512);
    cplain(tr_out_w, tr_out_wb, (size_t)4 * 512 * 512);
    cplain(tr_ff1_w, tr_ff1_wb, (size_t)4 * 2048 * 512);
    cplain(tr_ff2_w, tr_ff2_wb, (size_t)4 * 2048 * 512);
    cpad(adpt_w, adpt_wb, 512, 516, 576);
    cplain(post_lw, post_lwb, (size_t)6 * 512 * 512);
    cplain(post_mw, post_mwb, (size_t)6 * 512 * 512);
    cplain(cls_w1, cls_w1b, 512 * 512);

    // --- encoder ---
    gemm(xb, 128, enc0_wb, 128, enc0_b, /*R*/nullptr, /*C*/nullptr, /*Cb*/Hb,
         M, 512, 128, GB_WB16);
    for (int i = 0; i < 8; ++i) {
        gemm(Hb, 512, enc_lwb + (size_t)i * 262144, 512, enc_lb + (size_t)i * 512,
             /*R*/nullptr, /*C*/T1, /*Cb*/nullptr, M, 512, 512, GB_WF32);
        fsmn_means_b<<<dim3(2, 16, 8), dim3(256), 0, stream>>>(Hb, Mb, 1 << i);
        const int fl = GB_RES | GB_WB16 | (i == 7 ? GB_WF32 : 0);
        gemm(Mb, 512, enc_mwb + (size_t)i * 262144, 512, enc_mb + (size_t)i * 512,
             /*R*/T1, /*C*/H, /*Cb*/Hb, M, 512, 512, fl);
    }

    // --- speaker MLP ---
    gemm(spk_embb, 192, spk_w1b, 192, spk_b1, /*R*/nullptr, /*C*/nullptr, /*Cb*/S1b,
         32, 512, 192, GB_RELU | GB_WB16);
    gemm(S1b, 512, spk_w2b, 512, spk_b2, /*R*/nullptr, /*C*/nullptr, /*Cb*/S2b,
         32, 512, 512, GB_RELU | GB_WB16);
    gemm(S2b, 512, spk_w3b, 512, spk_b3, /*R*/nullptr, /*C*/S3, /*Cb*/nullptr,
         32, 512, 512, GB_WF32);

    // --- context-independent scores (from encoder Hb) ---
    ci_kernel<<<dim3(65536 / 256), dim3(256), 0, stream>>>(Hb, S3, CI);

    // --- transformer ---
    for (int i = 0; i < 4; ++i) {
        gemm(Hb, 512, tr_in_wb + (size_t)i * 786432, 512, tr_in_b + (size_t)i * 1536,
             /*R*/nullptr, /*C*/nullptr, /*Cb*/QKVb, M, 1536, 512, GB_WB16);
        vtprep<<<dim3(32, 32), dim3(256), 0, stream>>>(QKVb, Vt);
        attn_bf16<<<dim3(16, 32), dim3(512), 0, stream>>>(QKVb, Vt, AOb);
        gemm(AOb, 512, tr_out_wb + (size_t)i * 262144, 512, tr_out_b + (size_t)i * 512,
             /*R*/nullptr, /*C*/T1, /*Cb*/nullptr, M, 512, 512, GB_WF32);
        ln_add_f32<<<dim3(M / 4), dim3(256), 0, stream>>>(
            H, T1, tr_ln1_w + (size_t)i * 512, tr_ln1_b + (size_t)i * 512, H, Hb);
        gemm(Hb, 512, tr_ff1_wb + (size_t)i * 1048576, 512, tr_ff1_b + (size_t)i * 2048,
             /*R*/nullptr, /*C*/nullptr, /*Cb*/Fb, M, 2048, 512, GB_RELU | GB_WB16);
        gemm(Fb, 2048, tr_ff2_wb + (size_t)i * 1048576, 2048, tr_ff2_b + (size_t)i * 512,
             /*R*/nullptr, /*C*/T1, /*Cb*/nullptr, M, 512, 2048, GB_WF32);
        ln_add_f32<<<dim3(M / 4), dim3(256), 0, stream>>>(
            H, T1, tr_ln2_w + (size_t)i * 512, tr_ln2_b + (size_t)i * 512, H, Hb);
    }

    // --- concat + adapter ---
    concat_b<<<dim3((unsigned)(((size_t)M * 576 + 255) / 256)), dim3(256), 0, stream>>>(CI, Hb, Xcatb);
    gemm(Xcatb, 576, adpt_wb, 576, adpt_b, /*R*/nullptr, /*C*/nullptr, /*Cb*/Hb,
         M, 512, 576, GB_WB16);

    // --- post FSMN ---
    for (int i = 0; i < 6; ++i) {
        gemm(Hb, 512, post_lwb + (size_t)i * 262144, 512, post_lb + (size_t)i * 512,
             /*R*/nullptr, /*C*/T1, /*Cb*/nullptr, M, 512, 512, GB_WF32);
        fsmn_means_b<<<dim3(2, 16, 8), dim3(256), 0, stream>>>(Hb, Mb, 1 << i);
        gemm(Mb, 512, post_mwb + (size_t)i * 262144, 512, post_mb + (size_t)i * 512,
             /*R*/T1, /*C*/nullptr, /*Cb*/Hb, M, 512, 512, GB_RES | GB_WB16);
    }

    // --- classifier ---
    gemm(Hb, 512, cls_w1b, 512, cls_b1, /*R*/nullptr, /*C*/T1, /*Cb*/nullptr,
         M, 512, 512, GB_RELU | GB_WF32);
    cls2_kernel<<<dim3(M / 16), dim3(256), 0, stream>>>(T1, cls_w2, cls_b2, (float*)d_out);
}

// Round 6
// 3745.998 us; speedup vs baseline: 4.5391x; 1.2524x over previous
//
#include <hip/hip_runtime.h>
#include <hip/hip_bf16.h>
#include <math.h>

typedef unsigned short u16t;
using f32x4 = __attribute__((ext_vector_type(4))) float;
using s16x8 = __attribute__((ext_vector_type(8))) short;
using us8   = __attribute__((ext_vector_type(8))) unsigned short;

#define GB_RELU 1
#define GB_WF32 4
#define GB_WB16 8

__device__ __forceinline__ u16t f2b(float f) {
    unsigned u = __float_as_uint(f);
    unsigned r = (u + 0x7FFFu + ((u >> 16) & 1u)) >> 16;
    return (u16t)r;
}
__device__ __forceinline__ float b2f(u16t s) {
    return __uint_as_float(((unsigned)s) << 16);
}
__device__ __forceinline__ void gload16(const void* gsrc, void* ldst) {
    __builtin_amdgcn_global_load_lds(
        (const __attribute__((address_space(1))) void*)gsrc,
        (__attribute__((address_space(3))) void*)ldst, 16, 0, 0);
}

// ---------------------------------------------------------------------------
// bf16 MFMA GEMM, 2-phase pipelined, swizzled LDS, XCD-chunked block swizzle,
// LDS-staged coalesced bf16 epilogue.
// C[M,N] = A[M,K](bf16) @ W[N,K]^T(bf16) + bias; relu opt.
// 128x128 tile, BK=64, 256 thr (4 waves 2x2). K%64==0, N%128==0, M arbitrary.
// Params: A,lda, W,ldw, bias, C,ldc (fp32 out), Cb,ldcb (bf16 out), M,N,K,flags
// ---------------------------------------------------------------------------
__global__ __launch_bounds__(256)
void gemm_bf16(const u16t* __restrict__ A, int lda,
               const u16t* __restrict__ W, int ldw,
               const float* __restrict__ bias,
               float* __restrict__ C, int ldc,
               u16t* __restrict__ Cb, int ldcb,
               int M, int N, int K, int flags)
{
    __shared__ u16t SM[32768];          // 64 KiB: As[2][8192] | Ws[2][8192]
    u16t* As = SM;                      // As[buf] = SM + buf*8192
    u16t* Ws = SM + 16384;
    const int tid = threadIdx.x;
    const int lane = tid & 63, w = tid >> 6;
    const int wr = w >> 1, wc = w & 1;
    const int l15 = lane & 15, l4 = lane >> 4;

    // XCD-chunked bijective swizzle (only when nwg % 8 == 0)
    unsigned nwg = gridDim.x * gridDim.y;
    unsigned bid = blockIdx.y * gridDim.x + blockIdx.x;
    if ((nwg & 7u) == 0u) bid = (bid & 7u) * (nwg >> 3) + (bid >> 3);
    const int m0 = (int)(bid / gridDim.x) * 128;
    const int n0 = (int)(bid % gridDim.x) * 128;

    int arow[4], wrow[4], koff[4], se0[4];
#pragma unroll
    for (int it = 0; it < 4; ++it) {
        const int e = it * 256 + tid;
        se0[it] = it * 256 + (tid & 192);
        const int kb = e >> 7, r = e & 127;
        const int rg = r ^ (kb & 3);
        int gm = m0 + rg; if (gm > M - 1) gm = M - 1;
        arow[it] = gm;
        wrow[it] = n0 + rg;
        koff[it] = kb * 8;
    }

    f32x4 acc[4][4];
#pragma unroll
    for (int i = 0; i < 4; ++i)
#pragma unroll
        for (int j = 0; j < 4; ++j) acc[i][j] = (f32x4){0.f, 0.f, 0.f, 0.f};

    auto STAGE = [&](int buf, int k0) {
#pragma unroll
        for (int it = 0; it < 4; ++it)
            gload16(A + (size_t)arow[it] * lda + k0 + koff[it],
                    &As[(size_t)(buf * 8192 + se0[it] * 8)]);
#pragma unroll
        for (int it = 0; it < 4; ++it)
            gload16(W + (size_t)wrow[it] * ldw + k0 + koff[it],
                    &Ws[(size_t)(buf * 8192 + se0[it] * 8)]);
    };

    const int nk = K >> 6;
    STAGE(0, 0);
    for (int ks = 0; ks < nk; ++ks) {
        const int cur = ks & 1;
        if (ks + 1 < nk) {
            STAGE(cur ^ 1, (ks + 1) << 6);
            asm volatile("s_waitcnt vmcnt(8)" ::: "memory");
        } else {
            asm volatile("s_waitcnt vmcnt(0)" ::: "memory");
        }
        __builtin_amdgcn_s_barrier();
#pragma unroll
        for (int kk = 0; kk < 2; ++kk) {
            const int kb = kk * 4 + l4;
            const int ls = l15 ^ l4;     // swizzled row-within-16 on read
            s16x8 a[4], b[4];
#pragma unroll
            for (int mi = 0; mi < 4; ++mi)
                a[mi] = *(const s16x8*)&As[(size_t)(cur * 8192 + (kb * 128 + wr * 64 + mi * 16 + ls) * 8)];
#pragma unroll
            for (int ni = 0; ni < 4; ++ni)
                b[ni] = *(const s16x8*)&Ws[(size_t)(cur * 8192 + (kb * 128 + wc * 64 + ni * 16 + ls) * 8)];
#pragma unroll
            for (int mi = 0; mi < 4; ++mi)
#pragma unroll
                for (int ni = 0; ni < 4; ++ni)
                    acc[mi][ni] = __builtin_amdgcn_mfma_f32_16x16x32_bf16(
                        a[mi], b[ni], acc[mi][ni], 0, 0, 0);
        }
        __builtin_amdgcn_s_barrier();
    }

    // epilogue: compute bias/relu; fp32 direct; bf16 staged via LDS (stride 136)
    if (flags & GB_WB16) __syncthreads();   // staging LDS reuse-safe
#pragma unroll
    for (int mi = 0; mi < 4; ++mi) {
#pragma unroll
        for (int r = 0; r < 4; ++r) {
            const int rowl = wr * 64 + mi * 16 + l4 * 4 + r;
            const int row = m0 + rowl;
            const bool rok = row < M;
#pragma unroll
            for (int ni = 0; ni < 4; ++ni) {
                const int coll = wc * 64 + ni * 16 + l15;
                float v = acc[mi][ni][r];
                if (bias) v += bias[n0 + coll];
                if (flags & GB_RELU) v = fmaxf(v, 0.f);
                if ((flags & GB_WF32) && rok) C[(size_t)row * ldc + n0 + coll] = v;
                if (flags & GB_WB16) SM[rowl * 136 + coll] = f2b(v);
            }
        }
    }
    if (flags & GB_WB16) {
        __syncthreads();
#pragma unroll
        for (int rr = 0; rr < 8; ++rr) {
            const int rowl = rr * 16 + (tid >> 4);
            const int c0 = (tid & 15) * 8;
            if (m0 + rowl < M)
                *(us8*)(Cb + (size_t)(m0 + rowl) * ldcb + n0 + c0) =
                    *(const us8*)&SM[rowl * 136 + c0];
        }
    }
}

// ---------------------------------------------------------------------------
// FSMN sliding-window mean, in-place on HM[M,1024]: reads cols 0-511 (h),
// writes cols 512-1023 (means). grid (2,16,8), block 256.
// ---------------------------------------------------------------------------
__global__ __launch_bounds__(256)
void fsmn_means_b(u16t* __restrict__ HM, int stride)
{
    const int d = blockIdx.x * 256 + threadIdx.x;
    const int b = blockIdx.z;
    const int c0 = blockIdx.y * 128;
    const u16t* Hp = HM + (size_t)b * 2048 * 1024 + d;
    u16t* Mp = HM + (size_t)b * 2048 * 1024 + 512 + d;
    float sum = 0.f;
    int s0 = c0 - stride; if (s0 < 0) s0 = 0;
    for (int j = s0; j < c0; ++j) sum += b2f(Hp[(size_t)j * 1024]);
    for (int i = c0; i < c0 + 128; ++i) {
        sum += b2f(Hp[(size_t)i * 1024]);
        const int st = i - stride;
        const float cnt = (float)(i + 1 - (st > 0 ? st : 0));
        Mp[(size_t)i * 1024] = f2b(sum / cnt);
        if (st >= 0) sum -= b2f(Hp[(size_t)st * 1024]);
    }
}

// ---------------------------------------------------------------------------
// ci[b,l,s] = dot(HM[b,l,0:512], SF[b,s,:])   (HM ld 1024)
// ---------------------------------------------------------------------------
__global__ __launch_bounds__(256)
void ci_kernel(const u16t* __restrict__ HM, const float* __restrict__ SF,
               float* __restrict__ CI)
{
    const int idx = blockIdx.x * 256 + threadIdx.x;   // 65536
    const int s = idx & 3;
    const int bl = idx >> 2;
    const int b = bl >> 11;
    const us8* h8 = (const us8*)(HM + (size_t)bl * 1024);
    const float4* f4 = (const float4*)(SF + ((size_t)(b * 4 + s)) * 512);
    float acc = 0.f;
    for (int k = 0; k < 64; ++k) {
        const us8 hv = h8[k];
        const float4 f0 = f4[k * 2], f1 = f4[k * 2 + 1];
        acc += b2f(hv[0]) * f0.x + b2f(hv[1]) * f0.y + b2f(hv[2]) * f0.z + b2f(hv[3]) * f0.w
             + b2f(hv[4]) * f1.x + b2f(hv[5]) * f1.y + b2f(hv[6]) * f1.z + b2f(hv[7]) * f1.w;
    }
    CI[idx] = acc;
}

// ---------------------------------------------------------------------------
// Y(ld512,f32) = LN(X + R) * w + b ; Yb(ld1024,bf16) cols 0-511. 1 wave/row.
// ---------------------------------------------------------------------------
__global__ __launch_bounds__(256)
void ln_add_f32(const float* __restrict__ X, const float* __restrict__ R,
                const float* __restrict__ w, const float* __restrict__ b,
                float* __restrict__ Y, u16t* __restrict__ Yb)
{
    const int lane = threadIdx.x & 63, wid = threadIdx.x >> 6;
    const size_t row = (size_t)blockIdx.x * 4 + wid;
    const float* x = X + row * 512;
    const float* r = R + row * 512;
    const int c0 = lane * 8;
    float v[8];
    {
        const float4 a0 = *(const float4*)(x + c0);
        const float4 a1 = *(const float4*)(x + c0 + 4);
        const float4 r0 = *(const float4*)(r + c0);
        const float4 r1 = *(const float4*)(r + c0 + 4);
        v[0] = a0.x + r0.x; v[1] = a0.y + r0.y; v[2] = a0.z + r0.z; v[3] = a0.w + r0.w;
        v[4] = a1.x + r1.x; v[5] = a1.y + r1.y; v[6] = a1.z + r1.z; v[7] = a1.w + r1.w;
    }
    float s = 0.f;
#pragma unroll
    for (int j = 0; j < 8; ++j) s += v[j];
#pragma unroll
    for (int off = 1; off < 64; off <<= 1) s += __shfl_xor(s, off);
    const float mean = s * (1.f / 512.f);
    float q = 0.f;
#pragma unroll
    for (int j = 0; j < 8; ++j) { const float dd = v[j] - mean; q += dd * dd; }
#pragma unroll
    for (int off = 1; off < 64; off <<= 1) q += __shfl_xor(q, off);
    const float rstd = rsqrtf(q * (1.f / 512.f) + 1e-5f);
    float* y = Y + row * 512;
    u16t* yb = Yb + row * 1024;
#pragma unroll
    for (int j = 0; j < 8; ++j) {
        const float o = (v[j] - mean) * rstd * w[c0 + j] + b[c0 + j];
        y[c0 + j] = o;
        yb[c0 + j] = f2b(o);
    }
}

// ---------------------------------------------------------------------------
// V transpose: Vt[b,h,d,l] (bf16) from QKVb[b,l,1024+h*128+d] (bf16).
// grid (L/64, B*H), block 256.
// ---------------------------------------------------------------------------
__global__ __launch_bounds__(256)
void vtprep(const u16t* __restrict__ QKVb, u16t* __restrict__ Vt)
{
    __shared__ u16t T[128 * 72];
    const int tid = threadIdx.x;
    const int l0 = blockIdx.x * 64;
    const int bh = blockIdx.y, b = bh >> 2, h = bh & 3;
#pragma unroll
    for (int it = 0; it < 4; ++it) {
        const int e = it * 256 + tid;
        const int l = e >> 4, dc = e & 15;
        const us8 v = *(const us8*)(QKVb + ((size_t)(b * 2048 + l0 + l)) * 1536
                                   + 1024 + h * 128 + dc * 8);
#pragma unroll
        for (int j = 0; j < 8; ++j) T[(dc * 8 + j) * 72 + l] = v[j];
    }
    __syncthreads();
#pragma unroll
    for (int it = 0; it < 4; ++it) {
        const int e = it * 256 + tid;
        const int d = e >> 3, lc = e & 7;
        const us8 ov = *(const us8*)&T[d * 72 + lc * 8];
        *(us8*)(Vt + ((size_t)bh * 128 + d) * 2048 + l0 + lc * 8) = ov;
    }
}

// ---------------------------------------------------------------------------
// MFMA flash attention, 2-phase pipelined. grid (L/128, B*H), 512 thr.
// ---------------------------------------------------------------------------
__global__ __launch_bounds__(512)
void attn_bf16(const u16t* __restrict__ QKVb, const u16t* __restrict__ Vt,
               u16t* __restrict__ AOb)
{
    __shared__ u16t Kt[2][8192];
    __shared__ u16t Vtl[2][8192];
    __shared__ u16t Pl[8192];
    const int tid = threadIdx.x, lane = tid & 63, w = tid >> 6;
    const int l15 = lane & 15, l4 = lane >> 4;
    const int q0 = blockIdx.x * 128;
    const int bh = blockIdx.y, b = bh >> 2, h = bh & 3;
    const float SCALE = 0.08838834764831845f;   // 1/sqrt(128)

    int krow[2], kdoff[2], vd[2], vkoff[2], se0[2];
#pragma unroll
    for (int it = 0; it < 2; ++it) {
        const int e = it * 512 + tid;
        se0[it] = it * 512 + (tid & 448);
        const int dblk = e >> 6, key = e & 63;
        krow[it] = key ^ (dblk & 3);
        kdoff[it] = dblk * 8;
        const int kb = e >> 7, d = e & 127;
        vd[it] = d ^ (kb & 3);
        vkoff[it] = kb * 8;
    }
    auto STAGE = [&](int buf, int k0) {
#pragma unroll
        for (int it = 0; it < 2; ++it)
            gload16(QKVb + ((size_t)(b * 2048 + k0 + krow[it])) * 1536 + 512 + h * 128 + kdoff[it],
                    &Kt[buf][(size_t)se0[it] * 8]);
#pragma unroll
        for (int it = 0; it < 2; ++it)
            gload16(Vt + ((size_t)bh * 128 + vd[it]) * 2048 + k0 + vkoff[it],
                    &Vtl[buf][(size_t)se0[it] * 8]);
    };

    s16x8 qf[4];
    {
        const u16t* qp = QKVb + ((size_t)(b * 2048 + q0 + w * 16 + l15)) * 1536
                         + h * 128 + l4 * 8;
#pragma unroll
        for (int ks = 0; ks < 4; ++ks) qf[ks] = *(const s16x8*)(qp + ks * 32);
    }
    asm volatile("s_waitcnt vmcnt(0)" ::: "memory");

    f32x4 o[8];
#pragma unroll
    for (int i = 0; i < 8; ++i) o[i] = (f32x4){0.f, 0.f, 0.f, 0.f};
    f32x4 m_run, lsum;
#pragma unroll
    for (int r = 0; r < 4; ++r) { m_run[r] = -1e30f; lsum[r] = 0.f; }

    const int ls = l15 ^ l4;
    STAGE(0, 0);
    for (int kt = 0; kt < 32; ++kt) {
        const int cur = kt & 1;
        if (kt + 1 < 32) {
            STAGE(cur ^ 1, (kt + 1) * 64);
            asm volatile("s_waitcnt vmcnt(4)" ::: "memory");
        } else {
            asm volatile("s_waitcnt vmcnt(0)" ::: "memory");
        }
        __builtin_amdgcn_s_barrier();

        f32x4 s[4];
#pragma unroll
        for (int ni = 0; ni < 4; ++ni) s[ni] = (f32x4){0.f, 0.f, 0.f, 0.f};
#pragma unroll
        for (int ks = 0; ks < 4; ++ks) {
#pragma unroll
            for (int ni = 0; ni < 4; ++ni) {
                const s16x8 kf = *(const s16x8*)&Kt[cur][(size_t)((ks * 4 + l4) * 64 + ni * 16 + ls) * 8];
                s[ni] = __builtin_amdgcn_mfma_f32_16x16x32_bf16(qf[ks], kf, s[ni], 0, 0, 0);
            }
        }
        f32x4 mx;
#pragma unroll
        for (int r = 0; r < 4; ++r)
            mx[r] = fmaxf(fmaxf(s[0][r], s[1][r]), fmaxf(s[2][r], s[3][r])) * SCALE;
#pragma unroll
        for (int off = 1; off < 16; off <<= 1)
#pragma unroll
            for (int r = 0; r < 4; ++r) mx[r] = fmaxf(mx[r], __shfl_xor(mx[r], off));
        bool small = true;
#pragma unroll
        for (int r = 0; r < 4; ++r) small = small && (mx[r] <= m_run[r] + 8.f);
        if (!__all(small)) {
            f32x4 corr;
#pragma unroll
            for (int r = 0; r < 4; ++r) {
                const float nm = fmaxf(m_run[r], mx[r]);
                corr[r] = __expf(m_run[r] - nm);
                m_run[r] = nm;
                lsum[r] *= corr[r];
            }
#pragma unroll
            for (int ni = 0; ni < 8; ++ni)
#pragma unroll
                for (int r = 0; r < 4; ++r) o[ni][r] *= corr[r];
        }
        float p[4][4];
#pragma unroll
        for (int ni = 0; ni < 4; ++ni)
#pragma unroll
            for (int r = 0; r < 4; ++r) {
                p[ni][r] = __expf(s[ni][r] * SCALE - m_run[r]);
                lsum[r] += p[ni][r];
            }
#pragma unroll
        for (int ni = 0; ni < 4; ++ni) {
            const int key = ni * 16 + l15;
            const int kb = key >> 3, kj = key & 7;
#pragma unroll
            for (int r = 0; r < 4; ++r)
                Pl[(size_t)((w * 8 + kb) * 16 + l4 * 4 + r) * 8 + kj] = f2b(p[ni][r]);
        }
#pragma unroll
        for (int kk = 0; kk < 2; ++kk) {
            const s16x8 pa = *(const s16x8*)&Pl[(size_t)((w * 8 + kk * 4 + l4) * 16 + l15) * 8];
#pragma unroll
            for (int ni = 0; ni < 8; ++ni) {
                const s16x8 vf = *(const s16x8*)&Vtl[cur][(size_t)((kk * 4 + l4) * 128 + ni * 16 + ls) * 8];
                o[ni] = __builtin_amdgcn_mfma_f32_16x16x32_bf16(pa, vf, o[ni], 0, 0, 0);
            }
        }
        __builtin_amdgcn_s_barrier();
    }
#pragma unroll
    for (int off = 1; off < 16; off <<= 1)
#pragma unroll
        for (int r = 0; r < 4; ++r) lsum[r] += __shfl_xor(lsum[r], off);
    f32x4 inv;
#pragma unroll
    for (int r = 0; r < 4; ++r) inv[r] = 1.f / lsum[r];
#pragma unroll
    for (int ni = 0; ni < 8; ++ni)
#pragma unroll
        for (int r = 0; r < 4; ++r)
            AOb[((size_t)(b * 2048 + q0 + w * 16 + l4 * 4 + r)) * 512
                + h * 128 + ni * 16 + l15] = f2b(o[ni][r] * inv[r]);
}

// ---------------------------------------------------------------------------
// concat -> padded bf16 [M,576]: cols 0..3 = ci, 4..515 = HM h-cols, rest 0
// ---------------------------------------------------------------------------
__global__ __launch_bounds__(256)
void concat_b(const float* __restrict__ CI, const u16t* __restrict__ HM,
              u16t* __restrict__ OUTC)
{
    const size_t total = (size_t)16384 * 576;
    size_t i = (size_t)blockIdx.x * 256 + threadIdx.x;
    if (i >= total) return;
    const int col = (int)(i % 576);
    const size_t rowi = i / 576;
    u16t v = 0;
    if (col < 4) v = f2b(CI[rowi * 4 + col]);
    else if (col < 516) v = HM[rowi * 1024 + (col - 4)];
    OUTC[i] = v;
}

// ---------------------------------------------------------------------------
// converters
// ---------------------------------------------------------------------------
__global__ __launch_bounds__(256)
void cvt_plain(const float* __restrict__ src, u16t* __restrict__ dst, size_t n8)
{
    const size_t i = (size_t)blockIdx.x * 256 + threadIdx.x;
    if (i >= n8) return;
    const float4 a = ((const float4*)src)[i * 2];
    const float4 b = ((const float4*)src)[i * 2 + 1];
    us8 o;
    o[0] = f2b(a.x); o[1] = f2b(a.y); o[2] = f2b(a.z); o[3] = f2b(a.w);
    o[4] = f2b(b.x); o[5] = f2b(b.y); o[6] = f2b(b.z); o[7] = f2b(b.w);
    ((us8*)dst)[i] = o;
}

__global__ __launch_bounds__(256)
void cvt_pad(const float* __restrict__ src, u16t* __restrict__ dst,
             int rows, int sc, int dc)
{
    const size_t i = (size_t)blockIdx.x * 256 + threadIdx.x;
    const size_t total = (size_t)rows * dc;
    if (i >= total) return;
    const int c = (int)(i % dc);
    const size_t r = i / dc;
    dst[i] = (c < sc) ? f2b(src[r * sc + c]) : (u16t)0;
}

// fuse [layers,512,512] lw,mw -> [layers,512,1024] ([lw_row | mw_row])
__global__ __launch_bounds__(256)
void cvt_fuse(const float* __restrict__ lsrc, const float* __restrict__ msrc,
              u16t* __restrict__ dst, int n)
{
    const int idx = blockIdx.x * 256 + threadIdx.x;
    if (idx >= n) return;
    const int k = idx & 511;
    const int nn = (idx >> 9) & 511;
    const int i = idx >> 18;
    const size_t base = (size_t)i * 524288 + (size_t)nn * 1024 + k;
    dst[base] = f2b(lsrc[idx]);
    dst[base + 512] = f2b(msrc[idx]);
}

__global__ __launch_bounds__(256)
void bias_fuse(const float* __restrict__ a, const float* __restrict__ b,
               float* __restrict__ dst, int n)
{
    const int i = blockIdx.x * 256 + threadIdx.x;
    if (i < n) dst[i] = a[i] + b[i];
}

// ---------------------------------------------------------------------------
// final tiny GEMM: out[M,16] = T1[M,512] @ W2[16,512]^T + b2   (fp32)
// ---------------------------------------------------------------------------
__global__ __launch_bounds__(256)
void cls2_kernel(const float* __restrict__ T1, const float* __restrict__ W2,
                 const float* __restrict__ b2, float* __restrict__ out)
{
    const int t = threadIdx.x;
    const int r = blockIdx.x * 16 + (t >> 4), c = t & 15;
    const float4* a = (const float4*)(T1 + (size_t)r * 512);
    const float4* wv = (const float4*)(W2 + (size_t)c * 512);
    float acc = 0.f;
    for (int k = 0; k < 128; ++k) {
        const float4 x = a[k], y = wv[k];
        acc += x.x * y.x + x.y * y.y + x.z * y.z + x.w * y.w;
    }
    out[(size_t)r * 16 + c] = acc + b2[c];
}

// ---------------------------------------------------------------------------
extern "C" void kernel_launch(void* const* d_in, const int* in_sizes, int n_in,
                              void* d_out, int out_size, void* d_ws, size_t ws_size,
                              hipStream_t stream)
{
    (void)in_sizes; (void)n_in; (void)out_size; (void)ws_size;
    const int M = 16384;   // B*L

    const float* x        = (const float*)d_in[0];
    const float* spk_emb  = (const float*)d_in[1];
    const float* enc0_w   = (const float*)d_in[2];
    const float* enc0_b   = (const float*)d_in[3];
    const float* enc_lw   = (const float*)d_in[4];
    const float* enc_lb   = (const float*)d_in[5];
    const float* enc_mw   = (const float*)d_in[6];
    const float* enc_mb   = (const float*)d_in[7];
    const float* spk_w1   = (const float*)d_in[8];
    const float* spk_b1   = (const float*)d_in[9];
    const float* spk_w2   = (const float*)d_in[10];
    const float* spk_b2   = (const float*)d_in[11];
    const float* spk_w3   = (const float*)d_in[12];
    const float* spk_b3   = (const float*)d_in[13];
    const float* tr_in_w  = (const float*)d_in[14];
    const float* tr_in_b  = (const float*)d_in[15];
    const float* tr_out_w = (const float*)d_in[16];
    const float* tr_out_b = (const float*)d_in[17];
    const float* tr_ln1_w = (const float*)d_in[18];
    const float* tr_ln1_b = (const float*)d_in[19];
    const float* tr_ff1_w = (const float*)d_in[20];
    const float* tr_ff1_b = (const float*)d_in[21];
    const float* tr_ff2_w = (const float*)d_in[22];
    const float* tr_ff2_b = (const float*)d_in[23];
    const float* tr_ln2_w = (const float*)d_in[24];
    const float* tr_ln2_b = (const float*)d_in[25];
    const float* adpt_w   = (const float*)d_in[26];
    const float* adpt_b   = (const float*)d_in[27];
    const float* post_lw  = (const float*)d_in[28];
    const float* post_lb  = (const float*)d_in[29];
    const float* post_mw  = (const float*)d_in[30];
    const float* post_mb  = (const float*)d_in[31];
    const float* cls_w1   = (const float*)d_in[32];
    const float* cls_b1   = (const float*)d_in[33];
    const float* cls_w2   = (const float*)d_in[34];
    const float* cls_b2   = (const float*)d_in[35];

    // ---- workspace layout ----
    char* wsp = (char*)d_ws;
    size_t off = 0;
    auto alloc = [&](size_t bytes) -> void* {
        void* p = wsp + off; off += (bytes + 255) & ~(size_t)255; return p;
    };
    float* H    = (float*)alloc((size_t)M * 512 * 4);      // fp32 residual stream
    float* T1   = (float*)alloc((size_t)M * 512 * 4);      // fp32 pre-LN temp
    u16t*  HM0  = (u16t*) alloc((size_t)M * 1024 * 2);     // [h | means] ping
    u16t*  AOb  = (u16t*) alloc((size_t)M * 512 * 2);      // attn out
    u16t*  BIG  = (u16t*) alloc((size_t)M * 2048 * 2);     // HM1 | xb | QKV+Vt | F | Xcat
    float* CI   = (float*)alloc((size_t)M * 4 * 4);
    float* S3   = (float*)alloc(32 * 512 * 4);
    u16t* enc0_wb   = (u16t*)alloc(512 * 128 * 2);
    u16t* encFW     = (u16t*)alloc((size_t)8 * 512 * 1024 * 2);
    float* encFB    = (float*)alloc(8 * 512 * 4);
    u16t* spk_embb  = (u16t*)alloc(32 * 192 * 2);
    u16t* spk_w1b   = (u16t*)alloc(512 * 192 * 2);
    u16t* spk_w2b   = (u16t*)alloc(512 * 512 * 2);
    u16t* spk_w3b   = (u16t*)alloc(512 * 512 * 2);
    u16t* tr_in_wb  = (u16t*)alloc((size_t)4 * 1536 * 512 * 2);
    u16t* tr_out_wb = (u16t*)alloc((size_t)4 * 512 * 512 * 2);
    u16t* tr_ff1_wb = (u16t*)alloc((size_t)4 * 2048 * 512 * 2);
    u16t* tr_ff2_wb = (u16t*)alloc((size_t)4 * 2048 * 512 * 2);
    u16t* adpt_wb   = (u16t*)alloc(512 * 576 * 2);
    u16t* postFW    = (u16t*)alloc((size_t)6 * 512 * 1024 * 2);
    float* postFB   = (float*)alloc(6 * 512 * 4);
    u16t* cls_w1b   = (u16t*)alloc(512 * 512 * 2);
    u16t* S1b       = (u16t*)alloc(32 * 512 * 2);
    u16t* S2b       = (u16t*)alloc(32 * 512 * 2);

    u16t* HM1   = BIG;                       // [M,1024] during FSMN phases
    u16t* xb    = BIG;                       // [M,128] before enc0 only
    u16t* QKVb  = BIG;                       // [M,1536] during transformer
    u16t* Vt    = BIG + (size_t)M * 1536;    // [B*H,128,2048]
    u16t* Fb    = BIG;                       // [M,2048] FFN hidden
    u16t* Xcatb = BIG;                       // [M,576] concat
    u16t* HMs[2] = {HM0, HM1};

    auto cplain = [&](const float* s, u16t* d, size_t n) {
        const size_t n8 = n / 8;
        cvt_plain<<<dim3((unsigned)((n8 + 255) / 256)), dim3(256), 0, stream>>>(s, d, n8);
    };
    auto cpad = [&](const float* s, u16t* d, int rows, int sc, int dc) {
        const size_t tot = (size_t)rows * dc;
        cvt_pad<<<dim3((unsigned)((tot + 255) / 256)), dim3(256), 0, stream>>>(s, d, rows, sc, dc);
    };
    // 13 params: A,lda, W,ldw, bias, C,ldc, Cb,ldcb, m,n,k, flags
    auto gemm = [&](const u16t* A, int lda, const u16t* W, int ldw,
                    const float* bias, float* C, int ldc, u16t* Cb, int ldcb,
                    int m, int n, int k, int flags) {
        dim3 g(n / 128, (m + 127) / 128);
        gemm_bf16<<<g, dim3(256), 0, stream>>>(A, lda, W, ldw, bias,
                                               C, ldc, Cb, ldcb, m, n, k, flags);
    };

    // --- weight & input conversion ---
    cpad(x, xb, M, 80, 128);
    cpad(enc0_w, enc0_wb, 512, 80, 128);
    cvt_fuse<<<dim3(2097152 / 256), dim3(256), 0, stream>>>(enc_lw, enc_mw, encFW, 2097152);
    bias_fuse<<<dim3(16), dim3(256), 0, stream>>>(enc_lb, enc_mb, encFB, 4096);
    cplain(spk_emb, spk_embb, 32 * 192);
    cplain(spk_w1, spk_w1b, 512 * 192);
    cplain(spk_w2, spk_w2b, 512 * 512);
    cplain(spk_w3, spk_w3b, 512 * 512);
    cplain(tr_in_w, tr_in_wb, (size_t)4 * 1536 * 512);
    cplain(tr_out_w, tr_out_wb, (size_t)4 * 512 * 512);
    cplain(tr_ff1_w, tr_ff1_wb, (size_t)4 * 2048 * 512);
    cplain(tr_ff2_w, tr_ff2_wb, (size_t)4 * 2048 * 512);
    cpad(adpt_w, adpt_wb, 512, 516, 576);
    cvt_fuse<<<dim3(1572864 / 256), dim3(256), 0, stream>>>(post_lw, post_mw, postFW, 1572864);
    bias_fuse<<<dim3(12), dim3(256), 0, stream>>>(post_lb, post_mb, postFB, 3072);
    cplain(cls_w1, cls_w1b, 512 * 512);

    // --- encoder: enc0 writes h into HM0 cols 0-511 ---
    gemm(xb, 128, enc0_wb, 128, enc0_b,
         nullptr, 0, HM0, 1024, M, 512, 128, GB_WB16);
    for (int i = 0; i < 8; ++i) {   // strides 1,2,...,128; fused lin+mem GEMM
        u16t* src = HMs[i & 1];
        u16t* dst = HMs[(i + 1) & 1];
        fsmn_means_b<<<dim3(2, 16, 8), dim3(256), 0, stream>>>(src, 1 << i);
        gemm(src, 1024, encFW + (size_t)i * 524288, 1024, encFB + (size_t)i * 512,
             (i == 7 ? H : nullptr), 512, dst, 1024, M, 512, 1024,
             GB_WB16 | (i == 7 ? GB_WF32 : 0));
    }
    // h_enc now in HM0 (+ fp32 copy in H)

    // --- speaker MLP ---
    gemm(spk_embb, 192, spk_w1b, 192, spk_b1,
         nullptr, 0, S1b, 512, 32, 512, 192, GB_RELU | GB_WB16);
    gemm(S1b, 512, spk_w2b, 512, spk_b2,
         nullptr, 0, S2b, 512, 32, 512, 512, GB_RELU | GB_WB16);
    gemm(S2b, 512, spk_w3b, 512, spk_b3,
         S3, 512, nullptr, 0, 32, 512, 512, GB_WF32);

    // --- context-independent scores (from h_enc in HM0) ---
    ci_kernel<<<dim3(65536 / 256), dim3(256), 0, stream>>>(HM0, S3, CI);

    // --- transformer (h stream in HM0 cols 0-511, fp32 residual in H) ---
    for (int i = 0; i < 4; ++i) {
        gemm(HM0, 1024, tr_in_wb + (size_t)i * 786432, 512, tr_in_b + (size_t)i * 1536,
             nullptr, 0, QKVb, 1536, M, 1536, 512, GB_WB16);
        vtprep<<<dim3(32, 32), dim3(256), 0, stream>>>(QKVb, Vt);
        attn_bf16<<<dim3(16, 32), dim3(512), 0, stream>>>(QKVb, Vt, AOb);
        gemm(AOb, 512, tr_out_wb + (size_t)i * 262144, 512, tr_out_b + (size_t)i * 512,
             T1, 512, nullptr, 0, M, 512, 512, GB_WF32);
        ln_add_f32<<<dim3(M / 4), dim3(256), 0, stream>>>(
            H, T1, tr_ln1_w + (size_t)i * 512, tr_ln1_b + (size_t)i * 512, H, HM0);
        gemm(HM0, 1024, tr_ff1_wb + (size_t)i * 1048576, 512, tr_ff1_b + (size_t)i * 2048,
             nullptr, 0, Fb, 2048, M, 2048, 512, GB_RELU | GB_WB16);
        gemm(Fb, 2048, tr_ff2_wb + (size_t)i * 1048576, 2048, tr_ff2_b + (size_t)i * 512,
             T1, 512, nullptr, 0, M, 512, 2048, GB_WF32);
        ln_add_f32<<<dim3(M / 4), dim3(256), 0, stream>>>(
            H, T1, tr_ln2_w + (size_t)i * 512, tr_ln2_b + (size_t)i * 512, H, HM0);
    }

    // --- concat + adapter: write adapter output h into HM0 cols 0-511 ---
    concat_b<<<dim3((unsigned)(((size_t)M * 576 + 255) / 256)), dim3(256), 0, stream>>>(CI, HM0, Xcatb);
    gemm(Xcatb, 576, adpt_wb, 576, adpt_b,
         nullptr, 0, HM0, 1024, M, 512, 576, GB_WB16);

    // --- post FSMN (6 fused layers, strides 1..32) ---
    for (int i = 0; i < 6; ++i) {
        u16t* src = HMs[i & 1];
        u16t* dst = HMs[(i + 1) & 1];
        fsmn_means_b<<<dim3(2, 16, 8), dim3(256), 0, stream>>>(src, 1 << i);
        gemm(src, 1024, postFW + (size_t)i * 524288, 1024, postFB + (size_t)i * 512,
             nullptr, 0, dst, 1024, M, 512, 1024, GB_WB16);
    }
    // result in HM0

    // --- classifier ---
    gemm(HM0, 1024, cls_w1b, 512, cls_b1,
         T1, 512, nullptr, 0, M, 512, 512, GB_RELU | GB_WF32);
    cls2_kernel<<<dim3(M / 16), dim3(256), 0, stream>>>(T1, cls_w2, cls_b2, (float*)d_out);
}

// Round 7
// 3499.627 us; speedup vs baseline: 4.8587x; 1.0704x over previous
//
#include <hip/hip_runtime.h>
#include <hip/hip_bf16.h>
#include <math.h>

typedef unsigned short u16t;
using f32x4 = __attribute__((ext_vector_type(4))) float;
using s16x8 = __attribute__((ext_vector_type(8))) short;
using us8   = __attribute__((ext_vector_type(8))) unsigned short;

#define GB_RELU 1
#define GB_WF32 4
#define GB_WB16 8

__device__ __forceinline__ u16t f2b(float f) {
    unsigned u = __float_as_uint(f);
    unsigned r = (u + 0x7FFFu + ((u >> 16) & 1u)) >> 16;
    return (u16t)r;
}
__device__ __forceinline__ float b2f(u16t s) {
    return __uint_as_float(((unsigned)s) << 16);
}
__device__ __forceinline__ void gload16(const void* gsrc, void* ldst) {
    __builtin_amdgcn_global_load_lds(
        (const __attribute__((address_space(1))) void*)gsrc,
        (__attribute__((address_space(3))) void*)ldst, 16, 0, 0);
}

// ---------------------------------------------------------------------------
// bf16 MFMA GEMM, 2-phase pipelined, 8 waves (512 thr), swizzled LDS,
// XCD-chunked block swizzle, LDS-staged coalesced bf16 epilogue.
// C[M,N] = A[M,K](bf16) @ W[N,K]^T(bf16) + bias; relu opt.
// 128x128 tile, BK=64. Wave grid 2Mx4N, acc[4][2]/wave.
// K%64==0, N%128==0, M arbitrary.
// ---------------------------------------------------------------------------
__global__ __launch_bounds__(512)
void gemm_bf16(const u16t* __restrict__ A, int lda,
               const u16t* __restrict__ W, int ldw,
               const float* __restrict__ bias,
               float* __restrict__ C, int ldc,
               u16t* __restrict__ Cb, int ldcb,
               int M, int N, int K, int flags)
{
    __shared__ u16t SM[32768];          // 64 KiB: As[2][8192] | Ws[2][8192]
    u16t* As = SM;
    u16t* Ws = SM + 16384;
    const int tid = threadIdx.x;
    const int lane = tid & 63, w = tid >> 6;
    const int wr = w >> 2, wc = w & 3;       // 2M x 4N wave grid
    const int l15 = lane & 15, l4 = lane >> 4;

    // XCD-chunked bijective swizzle (only when nwg % 8 == 0)
    unsigned nwg = gridDim.x * gridDim.y;
    unsigned bid = blockIdx.y * gridDim.x + blockIdx.x;
    if ((nwg & 7u) == 0u) bid = (bid & 7u) * (nwg >> 3) + (bid >> 3);
    const int m0 = (int)(bid / gridDim.x) * 128;
    const int n0 = (int)(bid % gridDim.x) * 128;

    int arow[2], wrow[2], koff[2], se0[2];
#pragma unroll
    for (int it = 0; it < 2; ++it) {
        const int e = it * 512 + tid;          // element 0..1023 (16B units)
        se0[it] = it * 512 + (tid & 448);      // wave-uniform base
        const int kb = e >> 7, r = e & 127;
        const int rg = r ^ (kb & 3);
        int gm = m0 + rg; if (gm > M - 1) gm = M - 1;
        arow[it] = gm;
        wrow[it] = n0 + rg;
        koff[it] = kb * 8;
    }

    f32x4 acc[4][2];
#pragma unroll
    for (int i = 0; i < 4; ++i)
#pragma unroll
        for (int j = 0; j < 2; ++j) acc[i][j] = (f32x4){0.f, 0.f, 0.f, 0.f};

    auto STAGE = [&](int buf, int k0) {
#pragma unroll
        for (int it = 0; it < 2; ++it)
            gload16(A + (size_t)arow[it] * lda + k0 + koff[it],
                    &As[(size_t)(buf * 8192 + se0[it] * 8)]);
#pragma unroll
        for (int it = 0; it < 2; ++it)
            gload16(W + (size_t)wrow[it] * ldw + k0 + koff[it],
                    &Ws[(size_t)(buf * 8192 + se0[it] * 8)]);
    };

    const int nk = K >> 6;
    STAGE(0, 0);
    for (int ks = 0; ks < nk; ++ks) {
        const int cur = ks & 1;
        if (ks + 1 < nk) {
            STAGE(cur ^ 1, (ks + 1) << 6);
            asm volatile("s_waitcnt vmcnt(4)" ::: "memory");
        } else {
            asm volatile("s_waitcnt vmcnt(0)" ::: "memory");
        }
        __builtin_amdgcn_s_barrier();
#pragma unroll
        for (int kk = 0; kk < 2; ++kk) {
            const int kb = kk * 4 + l4;
            const int ls = l15 ^ l4;     // swizzled row-within-16 on read
            s16x8 a[4], b[2];
#pragma unroll
            for (int mi = 0; mi < 4; ++mi)
                a[mi] = *(const s16x8*)&As[(size_t)(cur * 8192 + (kb * 128 + wr * 64 + mi * 16 + ls) * 8)];
#pragma unroll
            for (int ni = 0; ni < 2; ++ni)
                b[ni] = *(const s16x8*)&Ws[(size_t)(cur * 8192 + (kb * 128 + wc * 32 + ni * 16 + ls) * 8)];
#pragma unroll
            for (int mi = 0; mi < 4; ++mi)
#pragma unroll
                for (int ni = 0; ni < 2; ++ni)
                    acc[mi][ni] = __builtin_amdgcn_mfma_f32_16x16x32_bf16(
                        a[mi], b[ni], acc[mi][ni], 0, 0, 0);
        }
        __builtin_amdgcn_s_barrier();
    }

    // epilogue
    if (flags & GB_WB16) __syncthreads();
#pragma unroll
    for (int mi = 0; mi < 4; ++mi) {
#pragma unroll
        for (int r = 0; r < 4; ++r) {
            const int rowl = wr * 64 + mi * 16 + l4 * 4 + r;
            const int row = m0 + rowl;
            const bool rok = row < M;
#pragma unroll
            for (int ni = 0; ni < 2; ++ni) {
                const int coll = wc * 32 + ni * 16 + l15;
                float v = acc[mi][ni][r];
                if (bias) v += bias[n0 + coll];
                if (flags & GB_RELU) v = fmaxf(v, 0.f);
                if ((flags & GB_WF32) && rok) C[(size_t)row * ldc + n0 + coll] = v;
                if (flags & GB_WB16) SM[rowl * 136 + coll] = f2b(v);
            }
        }
    }
    if (flags & GB_WB16) {
        __syncthreads();
#pragma unroll
        for (int rr = 0; rr < 4; ++rr) {
            const int rowl = rr * 32 + (tid >> 4);
            const int c0 = (tid & 15) * 8;
            if (m0 + rowl < M)
                *(us8*)(Cb + (size_t)(m0 + rowl) * ldcb + n0 + c0) =
                    *(const us8*)&SM[rowl * 136 + c0];
        }
    }
}

// ---------------------------------------------------------------------------
// FSMN sliding-window mean, in-place on HM[M,1024]: reads cols 0-511 (h),
// writes cols 512-1023 (means). grid (2,16,8), block 256.
// ---------------------------------------------------------------------------
__global__ __launch_bounds__(256)
void fsmn_means_b(u16t* __restrict__ HM, int stride)
{
    const int d = blockIdx.x * 256 + threadIdx.x;
    const int b = blockIdx.z;
    const int c0 = blockIdx.y * 128;
    const u16t* Hp = HM + (size_t)b * 2048 * 1024 + d;
    u16t* Mp = HM + (size_t)b * 2048 * 1024 + 512 + d;
    float sum = 0.f;
    int s0 = c0 - stride; if (s0 < 0) s0 = 0;
    for (int j = s0; j < c0; ++j) sum += b2f(Hp[(size_t)j * 1024]);
    for (int i = c0; i < c0 + 128; ++i) {
        sum += b2f(Hp[(size_t)i * 1024]);
        const int st = i - stride;
        const float cnt = (float)(i + 1 - (st > 0 ? st : 0));
        Mp[(size_t)i * 1024] = f2b(sum / cnt);
        if (st >= 0) sum -= b2f(Hp[(size_t)st * 1024]);
    }
}

// ---------------------------------------------------------------------------
// ci[b,l,s] = dot(HM[b,l,0:512], SF[b,s,:])   (HM ld 1024)
// ---------------------------------------------------------------------------
__global__ __launch_bounds__(256)
void ci_kernel(const u16t* __restrict__ HM, const float* __restrict__ SF,
               float* __restrict__ CI)
{
    const int idx = blockIdx.x * 256 + threadIdx.x;   // 65536
    const int s = idx & 3;
    const int bl = idx >> 2;
    const int b = bl >> 11;
    const us8* h8 = (const us8*)(HM + (size_t)bl * 1024);
    const float4* f4 = (const float4*)(SF + ((size_t)(b * 4 + s)) * 512);
    float acc = 0.f;
    for (int k = 0; k < 64; ++k) {
        const us8 hv = h8[k];
        const float4 f0 = f4[k * 2], f1 = f4[k * 2 + 1];
        acc += b2f(hv[0]) * f0.x + b2f(hv[1]) * f0.y + b2f(hv[2]) * f0.z + b2f(hv[3]) * f0.w
             + b2f(hv[4]) * f1.x + b2f(hv[5]) * f1.y + b2f(hv[6]) * f1.z + b2f(hv[7]) * f1.w;
    }
    CI[idx] = acc;
}

// ---------------------------------------------------------------------------
// Y(ld512,f32) = LN(X + R) * w + b ; Yb(ld1024,bf16) cols 0-511. 1 wave/row.
// ---------------------------------------------------------------------------
__global__ __launch_bounds__(256)
void ln_add_f32(const float* __restrict__ X, const float* __restrict__ R,
                const float* __restrict__ w, const float* __restrict__ b,
                float* __restrict__ Y, u16t* __restrict__ Yb)
{
    const int lane = threadIdx.x & 63, wid = threadIdx.x >> 6;
    const size_t row = (size_t)blockIdx.x * 4 + wid;
    const float* x = X + row * 512;
    const float* r = R + row * 512;
    const int c0 = lane * 8;
    float v[8];
    {
        const float4 a0 = *(const float4*)(x + c0);
        const float4 a1 = *(const float4*)(x + c0 + 4);
        const float4 r0 = *(const float4*)(r + c0);
        const float4 r1 = *(const float4*)(r + c0 + 4);
        v[0] = a0.x + r0.x; v[1] = a0.y + r0.y; v[2] = a0.z + r0.z; v[3] = a0.w + r0.w;
        v[4] = a1.x + r1.x; v[5] = a1.y + r1.y; v[6] = a1.z + r1.z; v[7] = a1.w + r1.w;
    }
    float s = 0.f;
#pragma unroll
    for (int j = 0; j < 8; ++j) s += v[j];
#pragma unroll
    for (int off = 1; off < 64; off <<= 1) s += __shfl_xor(s, off);
    const float mean = s * (1.f / 512.f);
    float q = 0.f;
#pragma unroll
    for (int j = 0; j < 8; ++j) { const float dd = v[j] - mean; q += dd * dd; }
#pragma unroll
    for (int off = 1; off < 64; off <<= 1) q += __shfl_xor(q, off);
    const float rstd = rsqrtf(q * (1.f / 512.f) + 1e-5f);
    float* y = Y + row * 512;
    u16t* yb = Yb + row * 1024;
#pragma unroll
    for (int j = 0; j < 8; ++j) {
        const float o = (v[j] - mean) * rstd * w[c0 + j] + b[c0 + j];
        y[c0 + j] = o;
        yb[c0 + j] = f2b(o);
    }
}

// ---------------------------------------------------------------------------
// V transpose: Vt[b,h,d,l] (bf16) from QKVb[b,l,1024+h*128+d] (bf16).
// grid (L/64, B*H), block 256.
// ---------------------------------------------------------------------------
__global__ __launch_bounds__(256)
void vtprep(const u16t* __restrict__ QKVb, u16t* __restrict__ Vt)
{
    __shared__ u16t T[128 * 72];
    const int tid = threadIdx.x;
    const int l0 = blockIdx.x * 64;
    const int bh = blockIdx.y, b = bh >> 2, h = bh & 3;
#pragma unroll
    for (int it = 0; it < 4; ++it) {
        const int e = it * 256 + tid;
        const int l = e >> 4, dc = e & 15;
        const us8 v = *(const us8*)(QKVb + ((size_t)(b * 2048 + l0 + l)) * 1536
                                   + 1024 + h * 128 + dc * 8);
#pragma unroll
        for (int j = 0; j < 8; ++j) T[(dc * 8 + j) * 72 + l] = v[j];
    }
    __syncthreads();
#pragma unroll
    for (int it = 0; it < 4; ++it) {
        const int e = it * 256 + tid;
        const int d = e >> 3, lc = e & 7;
        const us8 ov = *(const us8*)&T[d * 72 + lc * 8];
        *(us8*)(Vt + ((size_t)bh * 128 + d) * 2048 + l0 + lc * 8) = ov;
    }
}

// ---------------------------------------------------------------------------
// MFMA flash attention, 2-phase pipelined. grid (16, 32) = 512 blocks, 512 thr.
// XCD-grouped: xcd = bid&7 owns bh in {4*xcd .. 4*xcd+3} (K/V set = 4MB = L2).
// ---------------------------------------------------------------------------
__global__ __launch_bounds__(512)
void attn_bf16(const u16t* __restrict__ QKVb, const u16t* __restrict__ Vt,
               u16t* __restrict__ AOb)
{
    __shared__ u16t Kt[2][8192];
    __shared__ u16t Vtl[2][8192];
    __shared__ u16t Pl[8192];
    const int tid = threadIdx.x, lane = tid & 63, w = tid >> 6;
    const int l15 = lane & 15, l4 = lane >> 4;
    // XCD-aware remap: same-bh q-blocks land on one XCD
    const unsigned bid = blockIdx.y * gridDim.x + blockIdx.x;  // 0..511
    const int xcd = bid & 7, idx = bid >> 3;                   // idx 0..63
    const int bh = xcd * 4 + (idx & 3);
    const int q0 = (idx >> 2) * 128;
    const int b = bh >> 2, h = bh & 3;
    const float SCALE = 0.08838834764831845f;   // 1/sqrt(128)

    int krow[2], kdoff[2], vd[2], vkoff[2], se0[2];
#pragma unroll
    for (int it = 0; it < 2; ++it) {
        const int e = it * 512 + tid;
        se0[it] = it * 512 + (tid & 448);
        const int dblk = e >> 6, key = e & 63;
        krow[it] = key ^ (dblk & 3);
        kdoff[it] = dblk * 8;
        const int kb = e >> 7, d = e & 127;
        vd[it] = d ^ (kb & 3);
        vkoff[it] = kb * 8;
    }
    auto STAGE = [&](int buf, int k0) {
#pragma unroll
        for (int it = 0; it < 2; ++it)
            gload16(QKVb + ((size_t)(b * 2048 + k0 + krow[it])) * 1536 + 512 + h * 128 + kdoff[it],
                    &Kt[buf][(size_t)se0[it] * 8]);
#pragma unroll
        for (int it = 0; it < 2; ++it)
            gload16(Vt + ((size_t)bh * 128 + vd[it]) * 2048 + k0 + vkoff[it],
                    &Vtl[buf][(size_t)se0[it] * 8]);
    };

    s16x8 qf[4];
    {
        const u16t* qp = QKVb + ((size_t)(b * 2048 + q0 + w * 16 + l15)) * 1536
                         + h * 128 + l4 * 8;
#pragma unroll
        for (int ks = 0; ks < 4; ++ks) qf[ks] = *(const s16x8*)(qp + ks * 32);
    }
    asm volatile("s_waitcnt vmcnt(0)" ::: "memory");

    f32x4 o[8];
#pragma unroll
    for (int i = 0; i < 8; ++i) o[i] = (f32x4){0.f, 0.f, 0.f, 0.f};
    f32x4 m_run, lsum;
#pragma unroll
    for (int r = 0; r < 4; ++r) { m_run[r] = -1e30f; lsum[r] = 0.f; }

    const int ls = l15 ^ l4;
    STAGE(0, 0);
    for (int kt = 0; kt < 32; ++kt) {
        const int cur = kt & 1;
        if (kt + 1 < 32) {
            STAGE(cur ^ 1, (kt + 1) * 64);
            asm volatile("s_waitcnt vmcnt(4)" ::: "memory");
        } else {
            asm volatile("s_waitcnt vmcnt(0)" ::: "memory");
        }
        __builtin_amdgcn_s_barrier();

        f32x4 s[4];
#pragma unroll
        for (int ni = 0; ni < 4; ++ni) s[ni] = (f32x4){0.f, 0.f, 0.f, 0.f};
#pragma unroll
        for (int ks = 0; ks < 4; ++ks) {
#pragma unroll
            for (int ni = 0; ni < 4; ++ni) {
                const s16x8 kf = *(const s16x8*)&Kt[cur][(size_t)((ks * 4 + l4) * 64 + ni * 16 + ls) * 8];
                s[ni] = __builtin_amdgcn_mfma_f32_16x16x32_bf16(qf[ks], kf, s[ni], 0, 0, 0);
            }
        }
        f32x4 mx;
#pragma unroll
        for (int r = 0; r < 4; ++r)
            mx[r] = fmaxf(fmaxf(s[0][r], s[1][r]), fmaxf(s[2][r], s[3][r])) * SCALE;
#pragma unroll
        for (int off = 1; off < 16; off <<= 1)
#pragma unroll
            for (int r = 0; r < 4; ++r) mx[r] = fmaxf(mx[r], __shfl_xor(mx[r], off));
        bool small = true;
#pragma unroll
        for (int r = 0; r < 4; ++r) small = small && (mx[r] <= m_run[r] + 8.f);
        if (!__all(small)) {
            f32x4 corr;
#pragma unroll
            for (int r = 0; r < 4; ++r) {
                const float nm = fmaxf(m_run[r], mx[r]);
                corr[r] = __expf(m_run[r] - nm);
                m_run[r] = nm;
                lsum[r] *= corr[r];
            }
#pragma unroll
            for (int ni = 0; ni < 8; ++ni)
#pragma unroll
                for (int r = 0; r < 4; ++r) o[ni][r] *= corr[r];
        }
        float p[4][4];
#pragma unroll
        for (int ni = 0; ni < 4; ++ni)
#pragma unroll
            for (int r = 0; r < 4; ++r) {
                p[ni][r] = __expf(s[ni][r] * SCALE - m_run[r]);
                lsum[r] += p[ni][r];
            }
#pragma unroll
        for (int ni = 0; ni < 4; ++ni) {
            const int key = ni * 16 + l15;
            const int kb = key >> 3, kj = key & 7;
#pragma unroll
            for (int r = 0; r < 4; ++r)
                Pl[(size_t)((w * 8 + kb) * 16 + l4 * 4 + r) * 8 + kj] = f2b(p[ni][r]);
        }
#pragma unroll
        for (int kk = 0; kk < 2; ++kk) {
            const s16x8 pa = *(const s16x8*)&Pl[(size_t)((w * 8 + kk * 4 + l4) * 16 + l15) * 8];
#pragma unroll
            for (int ni = 0; ni < 8; ++ni) {
                const s16x8 vf = *(const s16x8*)&Vtl[cur][(size_t)((kk * 4 + l4) * 128 + ni * 16 + ls) * 8];
                o[ni] = __builtin_amdgcn_mfma_f32_16x16x32_bf16(pa, vf, o[ni], 0, 0, 0);
            }
        }
        __builtin_amdgcn_s_barrier();
    }
#pragma unroll
    for (int off = 1; off < 16; off <<= 1)
#pragma unroll
        for (int r = 0; r < 4; ++r) lsum[r] += __shfl_xor(lsum[r], off);
    f32x4 inv;
#pragma unroll
    for (int r = 0; r < 4; ++r) inv[r] = 1.f / lsum[r];
#pragma unroll
    for (int ni = 0; ni < 8; ++ni)
#pragma unroll
        for (int r = 0; r < 4; ++r)
            AOb[((size_t)(b * 2048 + q0 + w * 16 + l4 * 4 + r)) * 512
                + h * 128 + ni * 16 + l15] = f2b(o[ni][r] * inv[r]);
}

// ---------------------------------------------------------------------------
// concat -> padded bf16 [M,576]: cols 0..3 = ci, 4..515 = HM h-cols, rest 0
// ---------------------------------------------------------------------------
__global__ __launch_bounds__(256)
void concat_b(const float* __restrict__ CI, const u16t* __restrict__ HM,
              u16t* __restrict__ OUTC)
{
    const size_t total = (size_t)16384 * 576;
    size_t i = (size_t)blockIdx.x * 256 + threadIdx.x;
    if (i >= total) return;
    const int col = (int)(i % 576);
    const size_t rowi = i / 576;
    u16t v = 0;
    if (col < 4) v = f2b(CI[rowi * 4 + col]);
    else if (col < 516) v = HM[rowi * 1024 + (col - 4)];
    OUTC[i] = v;
}

// ---------------------------------------------------------------------------
// converters
// ---------------------------------------------------------------------------
__global__ __launch_bounds__(256)
void cvt_plain(const float* __restrict__ src, u16t* __restrict__ dst, size_t n8)
{
    const size_t i = (size_t)blockIdx.x * 256 + threadIdx.x;
    if (i >= n8) return;
    const float4 a = ((const float4*)src)[i * 2];
    const float4 b = ((const float4*)src)[i * 2 + 1];
    us8 o;
    o[0] = f2b(a.x); o[1] = f2b(a.y); o[2] = f2b(a.z); o[3] = f2b(a.w);
    o[4] = f2b(b.x); o[5] = f2b(b.y); o[6] = f2b(b.z); o[7] = f2b(b.w);
    ((us8*)dst)[i] = o;
}

__global__ __launch_bounds__(256)
void cvt_pad(const float* __restrict__ src, u16t* __restrict__ dst,
             int rows, int sc, int dc)
{
    const size_t i = (size_t)blockIdx.x * 256 + threadIdx.x;
    const size_t total = (size_t)rows * dc;
    if (i >= total) return;
    const int c = (int)(i % dc);
    const size_t r = i / dc;
    dst[i] = (c < sc) ? f2b(src[r * sc + c]) : (u16t)0;
}

// fuse [layers,512,512] lw,mw -> [layers,512,1024] ([lw_row | mw_row])
__global__ __launch_bounds__(256)
void cvt_fuse(const float* __restrict__ lsrc, const float* __restrict__ msrc,
              u16t* __restrict__ dst, int n)
{
    const int idx = blockIdx.x * 256 + threadIdx.x;
    if (idx >= n) return;
    const int k = idx & 511;
    const int nn = (idx >> 9) & 511;
    const int i = idx >> 18;
    const size_t base = (size_t)i * 524288 + (size_t)nn * 1024 + k;
    dst[base] = f2b(lsrc[idx]);
    dst[base + 512] = f2b(msrc[idx]);
}

__global__ __launch_bounds__(256)
void bias_fuse(const float* __restrict__ a, const float* __restrict__ b,
               float* __restrict__ dst, int n)
{
    const int i = blockIdx.x * 256 + threadIdx.x;
    if (i < n) dst[i] = a[i] + b[i];
}

// ---------------------------------------------------------------------------
// final tiny GEMM: out[M,16] = T1[M,512] @ W2[16,512]^T + b2   (fp32)
// ---------------------------------------------------------------------------
__global__ __launch_bounds__(256)
void cls2_kernel(const float* __restrict__ T1, const float* __restrict__ W2,
                 const float* __restrict__ b2, float* __restrict__ out)
{
    const int t = threadIdx.x;
    const int r = blockIdx.x * 16 + (t >> 4), c = t & 15;
    const float4* a = (const float4*)(T1 + (size_t)r * 512);
    const float4* wv = (const float4*)(W2 + (size_t)c * 512);
    float acc = 0.f;
    for (int k = 0; k < 128; ++k) {
        const float4 x = a[k], y = wv[k];
        acc += x.x * y.x + x.y * y.y + x.z * y.z + x.w * y.w;
    }
    out[(size_t)r * 16 + c] = acc + b2[c];
}

// ---------------------------------------------------------------------------
extern "C" void kernel_launch(void* const* d_in, const int* in_sizes, int n_in,
                              void* d_out, int out_size, void* d_ws, size_t ws_size,
                              hipStream_t stream)
{
    (void)in_sizes; (void)n_in; (void)out_size; (void)ws_size;
    const int M = 16384;   // B*L

    const float* x        = (const float*)d_in[0];
    const float* spk_emb  = (const float*)d_in[1];
    const float* enc0_w   = (const float*)d_in[2];
    const float* enc0_b   = (const float*)d_in[3];
    const float* enc_lw   = (const float*)d_in[4];
    const float* enc_lb   = (const float*)d_in[5];
    const float* enc_mw   = (const float*)d_in[6];
    const float* enc_mb   = (const float*)d_in[7];
    const float* spk_w1   = (const float*)d_in[8];
    const float* spk_b1   = (const float*)d_in[9];
    const float* spk_w2   = (const float*)d_in[10];
    const float* spk_b2   = (const float*)d_in[11];
    const float* spk_w3   = (const float*)d_in[12];
    const float* spk_b3   = (const float*)d_in[13];
    const float* tr_in_w  = (const float*)d_in[14];
    const float* tr_in_b  = (const float*)d_in[15];
    const float* tr_out_w = (const float*)d_in[16];
    const float* tr_out_b = (const float*)d_in[17];
    const float* tr_ln1_w = (const float*)d_in[18];
    const float* tr_ln1_b = (const float*)d_in[19];
    const float* tr_ff1_w = (const float*)d_in[20];
    const float* tr_ff1_b = (const float*)d_in[21];
    const float* tr_ff2_w = (const float*)d_in[22];
    const float* tr_ff2_b = (const float*)d_in[23];
    const float* tr_ln2_w = (const float*)d_in[24];
    const float* tr_ln2_b = (const float*)d_in[25];
    const float* adpt_w   = (const float*)d_in[26];
    const float* adpt_b   = (const float*)d_in[27];
    const float* post_lw  = (const float*)d_in[28];
    const float* post_lb  = (const float*)d_in[29];
    const float* post_mw  = (const float*)d_in[30];
    const float* post_mb  = (const float*)d_in[31];
    const float* cls_w1   = (const float*)d_in[32];
    const float* cls_b1   = (const float*)d_in[33];
    const float* cls_w2   = (const float*)d_in[34];
    const float* cls_b2   = (const float*)d_in[35];

    // ---- workspace layout ----
    char* wsp = (char*)d_ws;
    size_t off = 0;
    auto alloc = [&](size_t bytes) -> void* {
        void* p = wsp + off; off += (bytes + 255) & ~(size_t)255; return p;
    };
    float* H    = (float*)alloc((size_t)M * 512 * 4);      // fp32 residual stream
    float* T1   = (float*)alloc((size_t)M * 512 * 4);      // fp32 pre-LN temp
    u16t*  HM0  = (u16t*) alloc((size_t)M * 1024 * 2);     // [h | means] ping
    u16t*  AOb  = (u16t*) alloc((size_t)M * 512 * 2);      // attn out
    u16t*  BIG  = (u16t*) alloc((size_t)M * 2048 * 2);     // HM1 | xb | QKV+Vt | F | Xcat
    float* CI   = (float*)alloc((size_t)M * 4 * 4);
    float* S3   = (float*)alloc(32 * 512 * 4);
    u16t* enc0_wb   = (u16t*)alloc(512 * 128 * 2);
    u16t* encFW     = (u16t*)alloc((size_t)8 * 512 * 1024 * 2);
    float* encFB    = (float*)alloc(8 * 512 * 4);
    u16t* spk_embb  = (u16t*)alloc(32 * 192 * 2);
    u16t* spk_w1b   = (u16t*)alloc(512 * 192 * 2);
    u16t* spk_w2b   = (u16t*)alloc(512 * 512 * 2);
    u16t* spk_w3b   = (u16t*)alloc(512 * 512 * 2);
    u16t* tr_in_wb  = (u16t*)alloc((size_t)4 * 1536 * 512 * 2);
    u16t* tr_out_wb = (u16t*)alloc((size_t)4 * 512 * 512 * 2);
    u16t* tr_ff1_wb = (u16t*)alloc((size_t)4 * 2048 * 512 * 2);
    u16t* tr_ff2_wb = (u16t*)alloc((size_t)4 * 2048 * 512 * 2);
    u16t* adpt_wb   = (u16t*)alloc(512 * 576 * 2);
    u16t* postFW    = (u16t*)alloc((size_t)6 * 512 * 1024 * 2);
    float* postFB   = (float*)alloc(6 * 512 * 4);
    u16t* cls_w1b   = (u16t*)alloc(512 * 512 * 2);
    u16t* S1b       = (u16t*)alloc(32 * 512 * 2);
    u16t* S2b       = (u16t*)alloc(32 * 512 * 2);

    u16t* HM1   = BIG;                       // [M,1024] during FSMN phases
    u16t* xb    = BIG;                       // [M,128] before enc0 only
    u16t* QKVb  = BIG;                       // [M,1536] during transformer
    u16t* Vt    = BIG + (size_t)M * 1536;    // [B*H,128,2048]
    u16t* Fb    = BIG;                       // [M,2048] FFN hidden
    u16t* Xcatb = BIG;                       // [M,576] concat
    u16t* HMs[2] = {HM0, HM1};

    auto cplain = [&](const float* s, u16t* d, size_t n) {
        const size_t n8 = n / 8;
        cvt_plain<<<dim3((unsigned)((n8 + 255) / 256)), dim3(256), 0, stream>>>(s, d, n8);
    };
    auto cpad = [&](const float* s, u16t* d, int rows, int sc, int dc) {
        const size_t tot = (size_t)rows * dc;
        cvt_pad<<<dim3((unsigned)((tot + 255) / 256)), dim3(256), 0, stream>>>(s, d, rows, sc, dc);
    };
    // 13 params: A,lda, W,ldw, bias, C,ldc, Cb,ldcb, m,n,k, flags
    auto gemm = [&](const u16t* A, int lda, const u16t* W, int ldw,
                    const float* bias, float* C, int ldc, u16t* Cb, int ldcb,
                    int m, int n, int k, int flags) {
        dim3 g(n / 128, (m + 127) / 128);
        gemm_bf16<<<g, dim3(512), 0, stream>>>(A, lda, W, ldw, bias,
                                               C, ldc, Cb, ldcb, m, n, k, flags);
    };

    // --- weight & input conversion ---
    cpad(x, xb, M, 80, 128);
    cpad(enc0_w, enc0_wb, 512, 80, 128);
    cvt_fuse<<<dim3(2097152 / 256), dim3(256), 0, stream>>>(enc_lw, enc_mw, encFW, 2097152);
    bias_fuse<<<dim3(16), dim3(256), 0, stream>>>(enc_lb, enc_mb, encFB, 4096);
    cplain(spk_emb, spk_embb, 32 * 192);
    cplain(spk_w1, spk_w1b, 512 * 192);
    cplain(spk_w2, spk_w2b, 512 * 512);
    cplain(spk_w3, spk_w3b, 512 * 512);
    cplain(tr_in_w, tr_in_wb, (size_t)4 * 1536 * 512);
    cplain(tr_out_w, tr_out_wb, (size_t)4 * 512 * 512);
    cplain(tr_ff1_w, tr_ff1_wb, (size_t)4 * 2048 * 512);
    cplain(tr_ff2_w, tr_ff2_wb, (size_t)4 * 2048 * 512);
    cpad(adpt_w, adpt_wb, 512, 516, 576);
    cvt_fuse<<<dim3(1572864 / 256), dim3(256), 0, stream>>>(post_lw, post_mw, postFW, 1572864);
    bias_fuse<<<dim3(12), dim3(256), 0, stream>>>(post_lb, post_mb, postFB, 3072);
    cplain(cls_w1, cls_w1b, 512 * 512);

    // --- encoder: enc0 writes h into HM0 cols 0-511 ---
    gemm(xb, 128, enc0_wb, 128, enc0_b,
         nullptr, 0, HM0, 1024, M, 512, 128, GB_WB16);
    for (int i = 0; i < 8; ++i) {   // strides 1,2,...,128; fused lin+mem GEMM
        u16t* src = HMs[i & 1];
        u16t* dst = HMs[(i + 1) & 1];
        fsmn_means_b<<<dim3(2, 16, 8), dim3(256), 0, stream>>>(src, 1 << i);
        gemm(src, 1024, encFW + (size_t)i * 524288, 1024, encFB + (size_t)i * 512,
             (i == 7 ? H : nullptr), 512, dst, 1024, M, 512, 1024,
             GB_WB16 | (i == 7 ? GB_WF32 : 0));
    }
    // h_enc now in HM0 (+ fp32 copy in H)

    // --- speaker MLP ---
    gemm(spk_embb, 192, spk_w1b, 192, spk_b1,
         nullptr, 0, S1b, 512, 32, 512, 192, GB_RELU | GB_WB16);
    gemm(S1b, 512, spk_w2b, 512, spk_b2,
         nullptr, 0, S2b, 512, 32, 512, 512, GB_RELU | GB_WB16);
    gemm(S2b, 512, spk_w3b, 512, spk_b3,
         S3, 512, nullptr, 0, 32, 512, 512, GB_WF32);

    // --- context-independent scores (from h_enc in HM0) ---
    ci_kernel<<<dim3(65536 / 256), dim3(256), 0, stream>>>(HM0, S3, CI);

    // --- transformer (h stream in HM0 cols 0-511, fp32 residual in H) ---
    for (int i = 0; i < 4; ++i) {
        gemm(HM0, 1024, tr_in_wb + (size_t)i * 786432, 512, tr_in_b + (size_t)i * 1536,
             nullptr, 0, QKVb, 1536, M, 1536, 512, GB_WB16);
        vtprep<<<dim3(32, 32), dim3(256), 0, stream>>>(QKVb, Vt);
        attn_bf16<<<dim3(16, 32), dim3(512), 0, stream>>>(QKVb, Vt, AOb);
        gemm(AOb, 512, tr_out_wb + (size_t)i * 262144, 512, tr_out_b + (size_t)i * 512,
             T1, 512, nullptr, 0, M, 512, 512, GB_WF32);
        ln_add_f32<<<dim3(M / 4), dim3(256), 0, stream>>>(
            H, T1, tr_ln1_w + (size_t)i * 512, tr_ln1_b + (size_t)i * 512, H, HM0);
        gemm(HM0, 1024, tr_ff1_wb + (size_t)i * 1048576, 512, tr_ff1_b + (size_t)i * 2048,
             nullptr, 0, Fb, 2048, M, 2048, 512, GB_RELU | GB_WB16);
        gemm(Fb, 2048, tr_ff2_wb + (size_t)i * 1048576, 2048, tr_ff2_b + (size_t)i * 512,
             T1, 512, nullptr, 0, M, 512, 2048, GB_WF32);
        ln_add_f32<<<dim3(M / 4), dim3(256), 0, stream>>>(
            H, T1, tr_ln2_w + (size_t)i * 512, tr_ln2_b + (size_t)i * 512, H, HM0);
    }

    // --- concat + adapter: write adapter output h into HM0 cols 0-511 ---
    concat_b<<<dim3((unsigned)(((size_t)M * 576 + 255) / 256)), dim3(256), 0, stream>>>(CI, HM0, Xcatb);
    gemm(Xcatb, 576, adpt_wb, 576, adpt_b,
         nullptr, 0, HM0, 1024, M, 512, 576, GB_WB16);

    // --- post FSMN (6 fused layers, strides 1..32) ---
    for (int i = 0; i < 6; ++i) {
        u16t* src = HMs[i & 1];
        u16t* dst = HMs[(i + 1) & 1];
        fsmn_means_b<<<dim3(2, 16, 8), dim3(256), 0, stream>>>(src, 1 << i);
        gemm(src, 1024, postFW + (size_t)i * 524288, 1024, postFB + (size_t)i * 512,
             nullptr, 0, dst, 1024, M, 512, 1024, GB_WB16);
    }
    // result in HM0

    // --- classifier ---
    gemm(HM0, 1024, cls_w1b, 512, cls_b1,
         T1, 512, nullptr, 0, M, 512, 512, GB_RELU | GB_WF32);
    cls2_kernel<<<dim3(M / 16), dim3(256), 0, stream>>>(T1, cls_w2, cls_b2, (float*)d_out);
}